// Round 4
// baseline (10141.322 us; speedup 1.0000x reference)
//
#include <hip/hip_runtime.h>
#include <cfloat>
#include <climits>

#define DDIM 64
#define KSEL 16
#define NKB 32              // key blocks (8192 / 256)
#define SEED_SLICES 8
#define SEED_LEN 256        // queries per seed slice -> seed window 2048
#define SEED_N (SEED_SLICES * SEED_LEN)
#define MAIN_SLICES 30
#define MAIN_LEN 1024       // SEED_N + 30*1024 = 32768
#define SLOTS (1 + MAIN_SLICES)   // 31 partial lists per key
#define CHUNK 32            // queries staged per LDS chunk
#define CAP 12              // per-thread candidate buffer slots

// ---------------------------------------------------------------------------
// numpy pairwise-sum emulation for n=64 contiguous f32 (AVX512 npyv path).
// ---------------------------------------------------------------------------
__device__ __forceinline__ float np_sum64(const float* p) {
  float lane[16];
#pragma unroll
  for (int j = 0; j < 16; ++j)
    lane[j] = __fadd_rn(__fadd_rn(p[j], p[16 + j]),
                        __fadd_rn(p[32 + j], p[48 + j]));
  float u[8];
#pragma unroll
  for (int j = 0; j < 8; ++j) u[j] = __fadd_rn(lane[j], lane[j + 8]);
  float w[4];
#pragma unroll
  for (int j = 0; j < 4; ++j) w[j] = __fadd_rn(u[j], u[j + 4]);
  return __fadd_rn(__fadd_rn(w[0], w[2]), __fadd_rn(w[1], w[3]));
}

// Lexicographic (d, idx) bubble insert into sorted-ascending 16-reg list.
__device__ __forceinline__ void insert16(float* bd, int* bi, float cd, int ci) {
#pragma unroll
  for (int p = 0; p < KSEL; ++p) {
    bool sm = (cd < bd[p]) || (cd == bd[p] && ci < bi[p]);
    float td = bd[p]; int ti = bi[p];
    bd[p] = sm ? cd : td; bi[p] = sm ? ci : ti;
    cd = sm ? td : cd;   ci = sm ? ti : ci;
  }
}

// ---------------------------------------------------------------------------
// Kernel A: row norms emulating np.sum(a*a, axis=1) in f32
// ---------------------------------------------------------------------------
__global__ __launch_bounds__(256) void knn_norms_np(
    const float* __restrict__ keys, const float* __restrict__ queries,
    int Nk, int Nq, float* __restrict__ k2, float* __restrict__ q2) {
  int i = blockIdx.x * 256 + threadIdx.x;
  if (i >= Nk + Nq) return;
  const float* row = (i < Nk) ? keys + (size_t)i * DDIM
                              : queries + (size_t)(i - Nk) * DDIM;
  float p[DDIM];
#pragma unroll
  for (int t = 0; t < DDIM; ++t) p[t] = __fmul_rn(row[t], row[t]);
  float s = np_sum64(p);
  if (i < Nk) k2[i] = s; else q2[i - Nk] = s;
}

// ---------------------------------------------------------------------------
// Kernel B (seed): exact np-emulated top-16 over seed slices (first 2048 q),
// 8 slices x 256 queries. LDS-staged queries, full insert (cold start is
// cheap here: only 6% of all pairs). Writes slots 1..8.
// ---------------------------------------------------------------------------
__global__ __launch_bounds__(256, 3) void knn_seed(
    const float* __restrict__ keys, const float* __restrict__ queries,
    const float* __restrict__ k2a, const float* __restrict__ q2a,
    float* __restrict__ pd, int* __restrict__ pi) {
  __shared__ float qs[2][CHUNK * DDIM];
  int tid = threadIdx.x;
  int kb = blockIdx.x & (NKB - 1);
  int sl = blockIdx.x >> 5;            // 0..7
  int key = kb * 256 + tid;

  float4 kreg[16];
  const float4* kp = reinterpret_cast<const float4*>(keys + (size_t)key * DDIM);
#pragma unroll
  for (int t = 0; t < 16; ++t) kreg[t] = kp[t];
  float myk2 = k2a[key];

  float bd[KSEL]; int bi[KSEL];
#pragma unroll
  for (int p = 0; p < KSEL; ++p) { bd[p] = FLT_MAX; bi[p] = INT_MAX; }

  int j0 = sl * SEED_LEN;
  const int NC = SEED_LEN / CHUNK;     // 8
  const float4* g0 = reinterpret_cast<const float4*>(queries + (size_t)j0 * DDIM);
  float4 s0 = g0[tid * 2], s1 = g0[tid * 2 + 1];

  for (int c = 0; c < NC; ++c) {
    float4* buf = reinterpret_cast<float4*>(qs[c & 1]);
    buf[tid * 2] = s0; buf[tid * 2 + 1] = s1;
    __syncthreads();
    if (c + 1 < NC) {
      const float4* gn = reinterpret_cast<const float4*>(
          queries + (size_t)(j0 + (c + 1) * CHUNK) * DDIM);
      s0 = gn[tid * 2]; s1 = gn[tid * 2 + 1];
    }
    const float* qb = qs[c & 1];
    int jb = j0 + c * CHUNK;
    for (int qq = 0; qq < CHUNK; qq += 4) {
      const float4* r0 = reinterpret_cast<const float4*>(qb + (qq + 0) * DDIM);
      const float4* r1 = reinterpret_cast<const float4*>(qb + (qq + 1) * DDIM);
      const float4* r2 = reinterpret_cast<const float4*>(qb + (qq + 2) * DDIM);
      const float4* r3 = reinterpret_cast<const float4*>(qb + (qq + 3) * DDIM);
      float c0 = 0.f, c1 = 0.f, c2 = 0.f, c3 = 0.f;
#pragma unroll
      for (int t = 0; t < 16; ++t) {
        float4 a0 = r0[t], a1 = r1[t], a2 = r2[t], a3 = r3[t];
        float k0 = kreg[t].x, k1 = kreg[t].y, k2v = kreg[t].z, k3 = kreg[t].w;
        c0 = fmaf(k0, a0.x, c0); c1 = fmaf(k0, a1.x, c1);
        c2 = fmaf(k0, a2.x, c2); c3 = fmaf(k0, a3.x, c3);
        c0 = fmaf(k1, a0.y, c0); c1 = fmaf(k1, a1.y, c1);
        c2 = fmaf(k1, a2.y, c2); c3 = fmaf(k1, a3.y, c3);
        c0 = fmaf(k2v, a0.z, c0); c1 = fmaf(k2v, a1.z, c1);
        c2 = fmaf(k2v, a2.z, c2); c3 = fmaf(k2v, a3.z, c3);
        c0 = fmaf(k3, a0.w, c0); c1 = fmaf(k3, a1.w, c1);
        c2 = fmaf(k3, a2.w, c2); c3 = fmaf(k3, a3.w, c3);
      }
      float dots[4] = {c0, c1, c2, c3};
#pragma unroll
      for (int u = 0; u < 4; ++u) {
        float d2 = __fsub_rn(__fadd_rn(myk2, q2a[jb + qq + u]),
                             __fmul_rn(2.0f, dots[u]));
        if (d2 < bd[KSEL - 1]) insert16(bd, bi, d2, jb + qq + u);
      }
    }
    __syncthreads();
  }
  size_t base = ((size_t)key * SLOTS + 1 + sl) * KSEL;
#pragma unroll
  for (int p = 0; p < KSEL; ++p) { pd[base + p] = bd[p]; pi[base + p] = bi[p]; }
}

// ---------------------------------------------------------------------------
// Kernel C: per key, merge the 8 seed lists -> exact top-16 of first 2048.
// Write to slot 0 and threshold T[key] = 16th distance (upper bound on the
// global 16th).
// ---------------------------------------------------------------------------
__global__ __launch_bounds__(256) void knn_thresh(
    const float* __restrict__ pd_in, const int* __restrict__ pi_in,
    float* __restrict__ pd, int* __restrict__ pi, float* __restrict__ Tarr,
    int Nk) {
  int key = blockIdx.x * 256 + threadIdx.x;
  if (key >= Nk) return;
  float bd[KSEL]; int bi[KSEL];
#pragma unroll
  for (int p = 0; p < KSEL; ++p) { bd[p] = FLT_MAX; bi[p] = INT_MAX; }
  size_t base = (size_t)key * SLOTS * KSEL;
  for (int e = KSEL; e < (1 + SEED_SLICES) * KSEL; ++e) {
    float d = pd_in[base + e]; int id = pi_in[base + e];
    if (d < bd[KSEL - 1] || (d == bd[KSEL - 1] && id < bi[KSEL - 1]))
      insert16(bd, bi, d, id);
  }
#pragma unroll
  for (int p = 0; p < KSEL; ++p) { pd[base + p] = bd[p]; pi[base + p] = bi[p]; }
  Tarr[key] = bd[KSEL - 1];
}

// ---------------------------------------------------------------------------
// Kernel D (main): queries 2048..32767, 30 slices x 1024. Fixed threshold
// T[key]; passers (expected ~8/thread) buffered in LDS, spill-merged into
// reg top-16 when any lane's buffer nears full (synchronized, rare).
// ---------------------------------------------------------------------------
__global__ __launch_bounds__(256, 3) void knn_main(
    const float* __restrict__ keys, const float* __restrict__ queries,
    const float* __restrict__ k2a, const float* __restrict__ q2a,
    const float* __restrict__ Tarr,
    float* __restrict__ pd, int* __restrict__ pi) {
  __shared__ float qs[2][CHUNK * DDIM];   // 16 KB
  __shared__ uint2 cbuf[256 * CAP];       // 24 KB
  int tid = threadIdx.x;
  int kb = blockIdx.x & (NKB - 1);
  int sl = blockIdx.x >> 5;               // 0..29
  int key = kb * 256 + tid;

  float4 kreg[16];
  const float4* kp = reinterpret_cast<const float4*>(keys + (size_t)key * DDIM);
#pragma unroll
  for (int t = 0; t < 16; ++t) kreg[t] = kp[t];
  float myk2 = k2a[key];
  float T = Tarr[key];

  float bd[KSEL]; int bi[KSEL];
#pragma unroll
  for (int p = 0; p < KSEL; ++p) { bd[p] = FLT_MAX; bi[p] = INT_MAX; }
  int cnt = 0;
  uint2* mybuf = &cbuf[tid * CAP];

  int j0 = SEED_N + sl * MAIN_LEN;
  const int NC = MAIN_LEN / CHUNK;        // 32
  const float4* g0 = reinterpret_cast<const float4*>(queries + (size_t)j0 * DDIM);
  float4 s0 = g0[tid * 2], s1 = g0[tid * 2 + 1];

  for (int c = 0; c < NC; ++c) {
    float4* buf = reinterpret_cast<float4*>(qs[c & 1]);
    buf[tid * 2] = s0; buf[tid * 2 + 1] = s1;
    __syncthreads();
    if (c + 1 < NC) {
      const float4* gn = reinterpret_cast<const float4*>(
          queries + (size_t)(j0 + (c + 1) * CHUNK) * DDIM);
      s0 = gn[tid * 2]; s1 = gn[tid * 2 + 1];
    }
    const float* qb = qs[c & 1];
    int jb = j0 + c * CHUNK;
    for (int qq = 0; qq < CHUNK; qq += 4) {
      const float4* r0 = reinterpret_cast<const float4*>(qb + (qq + 0) * DDIM);
      const float4* r1 = reinterpret_cast<const float4*>(qb + (qq + 1) * DDIM);
      const float4* r2 = reinterpret_cast<const float4*>(qb + (qq + 2) * DDIM);
      const float4* r3 = reinterpret_cast<const float4*>(qb + (qq + 3) * DDIM);
      float c0 = 0.f, c1 = 0.f, c2 = 0.f, c3 = 0.f;
#pragma unroll
      for (int t = 0; t < 16; ++t) {
        float4 a0 = r0[t], a1 = r1[t], a2 = r2[t], a3 = r3[t];
        float k0 = kreg[t].x, k1 = kreg[t].y, k2v = kreg[t].z, k3 = kreg[t].w;
        c0 = fmaf(k0, a0.x, c0); c1 = fmaf(k0, a1.x, c1);
        c2 = fmaf(k0, a2.x, c2); c3 = fmaf(k0, a3.x, c3);
        c0 = fmaf(k1, a0.y, c0); c1 = fmaf(k1, a1.y, c1);
        c2 = fmaf(k1, a2.y, c2); c3 = fmaf(k1, a3.y, c3);
        c0 = fmaf(k2v, a0.z, c0); c1 = fmaf(k2v, a1.z, c1);
        c2 = fmaf(k2v, a2.z, c2); c3 = fmaf(k2v, a3.z, c3);
        c0 = fmaf(k3, a0.w, c0); c1 = fmaf(k3, a1.w, c1);
        c2 = fmaf(k3, a2.w, c2); c3 = fmaf(k3, a3.w, c3);
      }
      float dots[4] = {c0, c1, c2, c3};
#pragma unroll
      for (int u = 0; u < 4; ++u) {
        float d2 = __fsub_rn(__fadd_rn(myk2, q2a[jb + qq + u]),
                             __fmul_rn(2.0f, dots[u]));
        if (d2 < T) {
          mybuf[cnt] = make_uint2(__float_as_uint(d2), (unsigned)(jb + qq + u));
          cnt++;
        }
      }
      if (__any(cnt > CAP - 4)) {         // synchronized spill-merge
        for (int e = 0; e < cnt; ++e) {
          uint2 v = mybuf[e];
          float cd = __uint_as_float(v.x); int ci = (int)v.y;
          if (cd < bd[KSEL - 1] || (cd == bd[KSEL - 1] && ci < bi[KSEL - 1]))
            insert16(bd, bi, cd, ci);
        }
        cnt = 0;
      }
    }
    __syncthreads();
  }
  for (int e = 0; e < cnt; ++e) {
    uint2 v = mybuf[e];
    float cd = __uint_as_float(v.x); int ci = (int)v.y;
    if (cd < bd[KSEL - 1] || (cd == bd[KSEL - 1] && ci < bi[KSEL - 1]))
      insert16(bd, bi, cd, ci);
  }
  size_t base = ((size_t)key * SLOTS + 1 + sl) * KSEL;
#pragma unroll
  for (int p = 0; p < KSEL; ++p) { pd[base + p] = bd[p]; pi[base + p] = bi[p]; }
}

// ---------------------------------------------------------------------------
// Kernel E: final merge of all 31 slots per key -> top-16 indices (as float).
// ---------------------------------------------------------------------------
__global__ __launch_bounds__(256) void knn_merge(
    const float* __restrict__ pd, const int* __restrict__ pi,
    int Nk, float* __restrict__ outIdx) {
  int key = blockIdx.x * 256 + threadIdx.x;
  if (key >= Nk) return;
  float bd[KSEL]; int bi[KSEL];
#pragma unroll
  for (int p = 0; p < KSEL; ++p) { bd[p] = FLT_MAX; bi[p] = INT_MAX; }
  size_t base = (size_t)key * SLOTS * KSEL;
  int n = SLOTS * KSEL;
  for (int e = 0; e < n; ++e) {
    float d = pd[base + e]; int id = pi[base + e];
    if (d < bd[KSEL - 1] || (d == bd[KSEL - 1] && id < bi[KSEL - 1]))
      insert16(bd, bi, d, id);
  }
#pragma unroll
  for (int p = 0; p < KSEL; ++p)
    outIdx[(size_t)key * KSEL + p] = (float)bi[p];
}

// ---------------------------------------------------------------------------
// Kernel F: recompute distances sum((k-q)^2) in f64, emit f32.
// ---------------------------------------------------------------------------
__global__ __launch_bounds__(256) void knn_dist_d(
    const float* __restrict__ keys, const float* __restrict__ queries,
    const float* __restrict__ outIdx, int Nk, float* __restrict__ outDist) {
  int e = blockIdx.x * 256 + threadIdx.x;
  if (e >= Nk * KSEL) return;
  int key = e >> 4;
  int id = (int)outIdx[e];
  const float* kp = keys + (size_t)key * DDIM;
  const float* qp = queries + (size_t)id * DDIM;
  double s = 0.0;
#pragma unroll
  for (int t = 0; t < DDIM; ++t) {
    double d = (double)kp[t] - (double)qp[t];
    s = fma(d, d, s);
  }
  outDist[e] = (float)s;
}

// ---------------------------------------------------------------------------
extern "C" void kernel_launch(void* const* d_in, const int* in_sizes, int n_in,
                              void* d_out, int out_size, void* d_ws, size_t ws_size,
                              hipStream_t stream) {
  const float* keys    = (const float*)d_in[0];
  const float* queries = (const float*)d_in[1];
  int Nk = in_sizes[0] / DDIM;   // 8192
  int Nq = in_sizes[1] / DDIM;   // 32768
  float* out = (float*)d_out;

  // Workspace: pd f32[Nk*31*16] | pi i32[Nk*31*16] | k2[Nk] | q2[Nq] | T[Nk]
  size_t listElems = (size_t)Nk * SLOTS * KSEL;
  float* pd = (float*)d_ws;
  int*   pi = (int*)((char*)d_ws + listElems * 4);
  float* k2 = (float*)((char*)d_ws + listElems * 8);
  float* q2 = k2 + Nk;
  float* Ta = q2 + Nq;

  knn_norms_np<<<(Nk + Nq + 255) / 256, 256, 0, stream>>>(keys, queries, Nk, Nq, k2, q2);
  knn_seed<<<NKB * SEED_SLICES, 256, 0, stream>>>(keys, queries, k2, q2, pd, pi);
  knn_thresh<<<(Nk + 255) / 256, 256, 0, stream>>>(pd, pi, pd, pi, Ta, Nk);
  knn_main<<<NKB * MAIN_SLICES, 256, 0, stream>>>(keys, queries, k2, q2, Ta, pd, pi);
  knn_merge<<<(Nk + 255) / 256, 256, 0, stream>>>(pd, pi, Nk, out);
  knn_dist_d<<<(Nk * KSEL + 255) / 256, 256, 0, stream>>>(keys, queries, out, Nk,
                                                          out + (size_t)Nk * KSEL);
}

// Round 5
// 2096.094 us; speedup vs baseline: 4.8382x; 4.8382x over previous
//
#include <hip/hip_runtime.h>
#include <hip/hip_bf16.h>
#include <cfloat>
#include <climits>

#define DDIM 64
#define KSEL 16
#define NKB 32               // key blocks (8192/256)
#define SEED_SLICES 16
#define SEED_LEN 128         // seed window = 2048
#define SEED_N (SEED_SLICES * SEED_LEN)
#define SLOTS (1 + SEED_SLICES)
#define CHUNK 32
#define C1 0.017f            // > 2^-6: covers 2*bf16 dot error via Cauchy-Schwarz
#define C2 0.05f             // covers f32 accumulation + threshold rounding

typedef __attribute__((ext_vector_type(8))) short short8;
typedef __attribute__((ext_vector_type(4))) float f32x4;

// ---------------------------------------------------------------------------
// numpy pairwise-sum emulation for n=64 contiguous f32 (validated r3/r4).
// ---------------------------------------------------------------------------
__device__ __forceinline__ float np_sum64(const float* p) {
  float lane[16];
#pragma unroll
  for (int j = 0; j < 16; ++j)
    lane[j] = __fadd_rn(__fadd_rn(p[j], p[16 + j]),
                        __fadd_rn(p[32 + j], p[48 + j]));
  float u[8];
#pragma unroll
  for (int j = 0; j < 8; ++j) u[j] = __fadd_rn(lane[j], lane[j + 8]);
  float w[4];
#pragma unroll
  for (int j = 0; j < 4; ++j) w[j] = __fadd_rn(u[j], u[j + 4]);
  return __fadd_rn(__fadd_rn(w[0], w[2]), __fadd_rn(w[1], w[3]));
}

__device__ __forceinline__ void insert16(float* bd, int* bi, float cd, int ci) {
#pragma unroll
  for (int p = 0; p < KSEL; ++p) {
    bool sm = (cd < bd[p]) || (cd == bd[p] && ci < bi[p]);
    float td = bd[p]; int ti = bi[p];
    bd[p] = sm ? cd : td; bi[p] = sm ? ci : ti;
    cd = sm ? td : cd;   ci = sm ? ti : ci;
  }
}

// ---------------------------------------------------------------------------
// Kernel A: np-exact row norms + bf16 conversion + sqrt(q2).
// ---------------------------------------------------------------------------
__global__ __launch_bounds__(256) void knn_norms_np(
    const float* __restrict__ keys, const float* __restrict__ queries,
    int Nk, int Nq, float* __restrict__ k2, float* __restrict__ q2,
    float* __restrict__ sq, unsigned short* __restrict__ kbf,
    unsigned short* __restrict__ qbf) {
  int i = blockIdx.x * 256 + threadIdx.x;
  if (i >= Nk + Nq) return;
  bool isK = i < Nk;
  int r = isK ? i : i - Nk;
  const float* row = isK ? keys + (size_t)r * DDIM : queries + (size_t)r * DDIM;
  unsigned short* brow = (isK ? kbf : qbf) + (size_t)r * DDIM;
  float p[DDIM];
#pragma unroll
  for (int t = 0; t < DDIM; ++t) {
    float v = row[t];
    p[t] = __fmul_rn(v, v);
    __hip_bfloat16 h = __float2bfloat16(v);   // RNE
    brow[t] = *reinterpret_cast<const unsigned short*>(&h);
  }
  float s = np_sum64(p);
  if (isK) k2[r] = s;
  else { q2[r] = s; sq[r] = sqrtf(s); }
}

// ---------------------------------------------------------------------------
// Kernel B (seed): np-exact top-16 over seed window, 16 slices x 128 queries.
// Same validated structure as round 4's knn_seed. Writes slots 1..16.
// ---------------------------------------------------------------------------
__global__ __launch_bounds__(256) void knn_seed(
    const float* __restrict__ keys, const float* __restrict__ queries,
    const float* __restrict__ k2a, const float* __restrict__ q2a,
    float* __restrict__ pd, int* __restrict__ pi) {
  __shared__ float qs[2][CHUNK * DDIM];
  int tid = threadIdx.x;
  int kb = blockIdx.x & (NKB - 1);
  int sl = blockIdx.x >> 5;            // 0..15
  int key = kb * 256 + tid;

  float4 kreg[16];
  const float4* kp = reinterpret_cast<const float4*>(keys + (size_t)key * DDIM);
#pragma unroll
  for (int t = 0; t < 16; ++t) kreg[t] = kp[t];
  float myk2 = k2a[key];

  float bd[KSEL]; int bi[KSEL];
#pragma unroll
  for (int p = 0; p < KSEL; ++p) { bd[p] = FLT_MAX; bi[p] = INT_MAX; }

  int j0 = sl * SEED_LEN;
  const int NC = SEED_LEN / CHUNK;     // 4
  const float4* g0 = reinterpret_cast<const float4*>(queries + (size_t)j0 * DDIM);
  float4 s0 = g0[tid * 2], s1 = g0[tid * 2 + 1];

  for (int c = 0; c < NC; ++c) {
    float4* buf = reinterpret_cast<float4*>(qs[c & 1]);
    buf[tid * 2] = s0; buf[tid * 2 + 1] = s1;
    __syncthreads();
    if (c + 1 < NC) {
      const float4* gn = reinterpret_cast<const float4*>(
          queries + (size_t)(j0 + (c + 1) * CHUNK) * DDIM);
      s0 = gn[tid * 2]; s1 = gn[tid * 2 + 1];
    }
    const float* qb = qs[c & 1];
    int jb = j0 + c * CHUNK;
    for (int qq = 0; qq < CHUNK; qq += 4) {
      const float4* r0 = reinterpret_cast<const float4*>(qb + (qq + 0) * DDIM);
      const float4* r1 = reinterpret_cast<const float4*>(qb + (qq + 1) * DDIM);
      const float4* r2 = reinterpret_cast<const float4*>(qb + (qq + 2) * DDIM);
      const float4* r3 = reinterpret_cast<const float4*>(qb + (qq + 3) * DDIM);
      float c0 = 0.f, c1 = 0.f, c2 = 0.f, c3 = 0.f;
#pragma unroll
      for (int t = 0; t < 16; ++t) {
        float4 a0 = r0[t], a1 = r1[t], a2 = r2[t], a3 = r3[t];
        float k0 = kreg[t].x, k1 = kreg[t].y, k2v = kreg[t].z, k3 = kreg[t].w;
        c0 = fmaf(k0, a0.x, c0); c1 = fmaf(k0, a1.x, c1);
        c2 = fmaf(k0, a2.x, c2); c3 = fmaf(k0, a3.x, c3);
        c0 = fmaf(k1, a0.y, c0); c1 = fmaf(k1, a1.y, c1);
        c2 = fmaf(k1, a2.y, c2); c3 = fmaf(k1, a3.y, c3);
        c0 = fmaf(k2v, a0.z, c0); c1 = fmaf(k2v, a1.z, c1);
        c2 = fmaf(k2v, a2.z, c2); c3 = fmaf(k2v, a3.z, c3);
        c0 = fmaf(k3, a0.w, c0); c1 = fmaf(k3, a1.w, c1);
        c2 = fmaf(k3, a2.w, c2); c3 = fmaf(k3, a3.w, c3);
      }
      float dots[4] = {c0, c1, c2, c3};
#pragma unroll
      for (int u = 0; u < 4; ++u) {
        float d2 = __fsub_rn(__fadd_rn(myk2, q2a[jb + qq + u]),
                             __fmul_rn(2.0f, dots[u]));
        if (d2 < bd[KSEL - 1]) insert16(bd, bi, d2, jb + qq + u);
      }
    }
    __syncthreads();
  }
  size_t base = ((size_t)key * SLOTS + 1 + sl) * KSEL;
#pragma unroll
  for (int p = 0; p < KSEL; ++p) { pd[base + p] = bd[p]; pi[base + p] = bi[p]; }
}

// ---------------------------------------------------------------------------
// Kernel C: merge 16 seed lists -> slot 0 (exact top-16 of first 2048) and
// per-key filter constants PS = { k2 - T - C2, -C1*sqrt(k2) }.
// ---------------------------------------------------------------------------
__global__ __launch_bounds__(256) void knn_thresh(
    const float* __restrict__ pd_in, const int* __restrict__ pi_in,
    const float* __restrict__ k2a,
    float* __restrict__ pd, int* __restrict__ pi, float2* __restrict__ PS,
    int Nk) {
  int key = blockIdx.x * 256 + threadIdx.x;
  if (key >= Nk) return;
  float bd[KSEL]; int bi[KSEL];
#pragma unroll
  for (int p = 0; p < KSEL; ++p) { bd[p] = FLT_MAX; bi[p] = INT_MAX; }
  size_t base = (size_t)key * SLOTS * KSEL;
  for (int e = KSEL; e < SLOTS * KSEL; ++e) {
    float d = pd_in[base + e]; int id = pi_in[base + e];
    if (d < bd[KSEL - 1] || (d == bd[KSEL - 1] && id < bi[KSEL - 1]))
      insert16(bd, bi, d, id);
  }
#pragma unroll
  for (int p = 0; p < KSEL; ++p) { pd[base + p] = bd[p]; pi[base + p] = bi[p]; }
  float k2 = k2a[key];
  float T = bd[KSEL - 1];
  PS[key] = make_float2(k2 - T - C2, -C1 * sqrtf(k2));
}

// ---------------------------------------------------------------------------
__global__ __launch_bounds__(256) void knn_zero(unsigned* __restrict__ p, int n) {
  int i = blockIdx.x * 256 + threadIdx.x;
  if (i < n) p[i] = 0u;
}

// ---------------------------------------------------------------------------
// Kernel D (MFMA filter): queries SEED_N..32767. One wave = 64 keys x 16
// queries (4 stacked 16x16x32 bf16 MFMA tiles, K=64 in two halves).
// Emit query index to key's bucket when dot > thr  <=>  approx_d2 < T+margin.
// A layout: lane holds A[row=l&15][k=(l>>4)*8 .. +7]; B: B[col=l&15][same k].
// C/D: col = lane&15 (query), row = (lane>>4)*4 + reg (key)  [HW-verified].
// ---------------------------------------------------------------------------
__global__ __launch_bounds__(256) void knn_filter(
    const unsigned short* __restrict__ kbf, const unsigned short* __restrict__ qbf,
    const float* __restrict__ q2a, const float* __restrict__ sqa,
    const float2* __restrict__ PS,
    unsigned* __restrict__ cnt, unsigned short* __restrict__ cbuf, int CAP) {
  int tid = threadIdx.x;
  int lane = tid & 63, w = tid >> 6;
  int kb = blockIdx.x & (NKB - 1);
  int qt = blockIdx.x >> 5;
  int qbase = SEED_N + qt * 16;
  int kbase = kb * 256 + w * 64;
  int l16 = lane & 15, lg = lane >> 4;
  int q = qbase + l16;

  const short8* qrow = reinterpret_cast<const short8*>(qbf + (size_t)q * DDIM);
  short8 b0 = qrow[lg];        // k = lg*8 .. +7
  short8 b1 = qrow[lg + 4];    // k = 32 + lg*8 .. +7
  float q2l = q2a[q], sql = sqa[q];

  f32x4 acc[4];
#pragma unroll
  for (int s = 0; s < 4; ++s) {
    const short8* krow = reinterpret_cast<const short8*>(
        kbf + (size_t)(kbase + s * 16 + l16) * DDIM);
    short8 a0 = krow[lg], a1 = krow[lg + 4];
    f32x4 z = {0.f, 0.f, 0.f, 0.f};
    z = __builtin_amdgcn_mfma_f32_16x16x32_bf16(a0, b0, z, 0, 0, 0);
    z = __builtin_amdgcn_mfma_f32_16x16x32_bf16(a1, b1, z, 0, 0, 0);
    acc[s] = z;
  }
#pragma unroll
  for (int s = 0; s < 4; ++s) {
    int krow0 = kbase + s * 16 + lg * 4;
#pragma unroll
    for (int r = 0; r < 4; ++r) {
      float2 ps = PS[krow0 + r];
      float thr = 0.5f * ((ps.x + q2l) + ps.y * sql);
      if (acc[s][r] > thr) {
        int key = krow0 + r;
        unsigned pos = atomicAdd(&cnt[key], 1u);
        if (pos < (unsigned)CAP) cbuf[(size_t)key * CAP + pos] = (unsigned short)q;
      }
    }
  }
}

// ---------------------------------------------------------------------------
// Kernel E (recheck): thread per key. np-exact d2 for each candidate
// (sequential fmaf chain, identical to validated seed arithmetic), lex-merge
// with seed top-16. Overflow => exact full scan fallback (correctness net).
// ---------------------------------------------------------------------------
__global__ __launch_bounds__(256) void knn_recheck(
    const float* __restrict__ keys, const float* __restrict__ queries,
    const float* __restrict__ k2a, const float* __restrict__ q2a,
    const float* __restrict__ pd, const int* __restrict__ pi,
    const unsigned* __restrict__ cnt, const unsigned short* __restrict__ cbuf,
    int CAP, int Nk, int Nq, float* __restrict__ outIdx) {
  int key = blockIdx.x * 256 + threadIdx.x;
  if (key >= Nk) return;
  float bd[KSEL]; int bi[KSEL];
  size_t base = (size_t)key * SLOTS * KSEL;
#pragma unroll
  for (int p = 0; p < KSEL; ++p) { bd[p] = pd[base + p]; bi[p] = pi[base + p]; }
  float myk2 = k2a[key];
  const float* krow = keys + (size_t)key * DDIM;
  unsigned n = cnt[key];
  if (n <= (unsigned)CAP) {
    const unsigned short* mc = cbuf + (size_t)key * CAP;
    for (unsigned e = 0; e < n; ++e) {
      int j = mc[e];
      const float* qrow = queries + (size_t)j * DDIM;
      float c = 0.f;
#pragma unroll
      for (int t = 0; t < DDIM; ++t) c = fmaf(krow[t], qrow[t], c);
      float d2 = __fsub_rn(__fadd_rn(myk2, q2a[j]), __fmul_rn(2.0f, c));
      if (d2 < bd[KSEL - 1] || (d2 == bd[KSEL - 1] && j < bi[KSEL - 1]))
        insert16(bd, bi, d2, j);
    }
  } else {
    for (int j = SEED_N; j < Nq; ++j) {
      const float* qrow = queries + (size_t)j * DDIM;
      float c = 0.f;
#pragma unroll
      for (int t = 0; t < DDIM; ++t) c = fmaf(krow[t], qrow[t], c);
      float d2 = __fsub_rn(__fadd_rn(myk2, q2a[j]), __fmul_rn(2.0f, c));
      if (d2 < bd[KSEL - 1] || (d2 == bd[KSEL - 1] && j < bi[KSEL - 1]))
        insert16(bd, bi, d2, j);
    }
  }
#pragma unroll
  for (int p = 0; p < KSEL; ++p)
    outIdx[(size_t)key * KSEL + p] = (float)bi[p];
}

// ---------------------------------------------------------------------------
// Kernel F: recompute distances sum((k-q)^2) in f64, emit f32 (validated).
// ---------------------------------------------------------------------------
__global__ __launch_bounds__(256) void knn_dist_d(
    const float* __restrict__ keys, const float* __restrict__ queries,
    const float* __restrict__ outIdx, int Nk, float* __restrict__ outDist) {
  int e = blockIdx.x * 256 + threadIdx.x;
  if (e >= Nk * KSEL) return;
  int key = e >> 4;
  int id = (int)outIdx[e];
  const float* kp = keys + (size_t)key * DDIM;
  const float* qp = queries + (size_t)id * DDIM;
  double s = 0.0;
#pragma unroll
  for (int t = 0; t < DDIM; ++t) {
    double d = (double)kp[t] - (double)qp[t];
    s = fma(d, d, s);
  }
  outDist[e] = (float)s;
}

// ---------------------------------------------------------------------------
extern "C" void kernel_launch(void* const* d_in, const int* in_sizes, int n_in,
                              void* d_out, int out_size, void* d_ws, size_t ws_size,
                              hipStream_t stream) {
  const float* keys    = (const float*)d_in[0];
  const float* queries = (const float*)d_in[1];
  int Nk = in_sizes[0] / DDIM;   // 8192
  int Nq = in_sizes[1] / DDIM;   // 32768
  float* out = (float*)d_out;

  // Workspace layout (ws >= 32.7MB proven by round 4):
  size_t listElems = (size_t)Nk * SLOTS * KSEL;            // 2,228,224
  char* wp = (char*)d_ws;
  float*          pd  = (float*)wp;                wp += listElems * 4;
  int*            pi  = (int*)wp;                  wp += listElems * 4;
  float*          k2  = (float*)wp;                wp += (size_t)Nk * 4;
  float*          q2  = (float*)wp;                wp += (size_t)Nq * 4;
  float*          sq  = (float*)wp;                wp += (size_t)Nq * 4;
  float2*         PS  = (float2*)wp;               wp += (size_t)Nk * 8;
  unsigned*       cnt = (unsigned*)wp;             wp += (size_t)Nk * 4;
  unsigned short* kbf = (unsigned short*)wp;       wp += (size_t)Nk * DDIM * 2;
  unsigned short* qbf = (unsigned short*)wp;       wp += (size_t)Nq * DDIM * 2;
  size_t fixedBytes = (size_t)(wp - (char*)d_ws);
  unsigned short* cbuf = (unsigned short*)wp;
  long long rem = (long long)ws_size - (long long)fixedBytes;
  int CAP = (int)(rem / (2 * (long long)Nk));
  if (CAP > 2048) CAP = 2048;
  if (CAP < 16) CAP = 16;

  int NQT = (Nq - SEED_N) / 16;   // 1920

  knn_norms_np<<<(Nk + Nq + 255) / 256, 256, 0, stream>>>(
      keys, queries, Nk, Nq, k2, q2, sq, kbf, qbf);
  knn_seed<<<NKB * SEED_SLICES, 256, 0, stream>>>(keys, queries, k2, q2, pd, pi);
  knn_thresh<<<(Nk + 255) / 256, 256, 0, stream>>>(pd, pi, k2, pd, pi, PS, Nk);
  knn_zero<<<(Nk + 255) / 256, 256, 0, stream>>>(cnt, Nk);
  knn_filter<<<NKB * NQT, 256, 0, stream>>>(kbf, qbf, q2, sq, PS, cnt, cbuf, CAP);
  knn_recheck<<<(Nk + 255) / 256, 256, 0, stream>>>(
      keys, queries, k2, q2, pd, pi, cnt, cbuf, CAP, Nk, Nq, out);
  knn_dist_d<<<(Nk * KSEL + 255) / 256, 256, 0, stream>>>(
      keys, queries, out, Nk, out + (size_t)Nk * KSEL);
}

// Round 6
// 1058.549 us; speedup vs baseline: 9.5804x; 1.9802x over previous
//
#include <hip/hip_runtime.h>
#include <hip/hip_bf16.h>
#include <cfloat>
#include <climits>

#define DDIM 64
#define KSEL 16
#define NKB 32               // key blocks (8192/256)
#define SEED_SLICES 16
#define SEED_LEN 128         // seed window = 2048
#define SEED_N (SEED_SLICES * SEED_LEN)
#define SLOTS (1 + SEED_SLICES)
#define CHUNK 32
#define C1 0.017f            // > 2^-6: covers 2*bf16 dot error via Cauchy-Schwarz
#define C2 0.05f             // covers f32 accumulation + threshold rounding
#define MERGE_MAX 1008       // fast-path candidate limit for rank-merge buffer
#define RBUF (KSEL + 64 * KSEL)  // 1040 pack slots/wave (fallback worst case)

typedef __attribute__((ext_vector_type(8))) short short8;
typedef __attribute__((ext_vector_type(4))) float f32x4;

// ---------------------------------------------------------------------------
// numpy pairwise-sum emulation for n=64 contiguous f32 (validated r3-r5).
// ---------------------------------------------------------------------------
__device__ __forceinline__ float np_sum64(const float* p) {
  float lane[16];
#pragma unroll
  for (int j = 0; j < 16; ++j)
    lane[j] = __fadd_rn(__fadd_rn(p[j], p[16 + j]),
                        __fadd_rn(p[32 + j], p[48 + j]));
  float u[8];
#pragma unroll
  for (int j = 0; j < 8; ++j) u[j] = __fadd_rn(lane[j], lane[j + 8]);
  float w[4];
#pragma unroll
  for (int j = 0; j < 4; ++j) w[j] = __fadd_rn(u[j], u[j + 4]);
  return __fadd_rn(__fadd_rn(w[0], w[2]), __fadd_rn(w[1], w[3]));
}

__device__ __forceinline__ void insert16(float* bd, int* bi, float cd, int ci) {
#pragma unroll
  for (int p = 0; p < KSEL; ++p) {
    bool sm = (cd < bd[p]) || (cd == bd[p] && ci < bi[p]);
    float td = bd[p]; int ti = bi[p];
    bd[p] = sm ? cd : td; bi[p] = sm ? ci : ti;
    cd = sm ? td : cd;   ci = sm ? ti : ci;
  }
}

// Monotone map: lexicographic (d,j) ascending == u64 ascending (j distinct).
__device__ __forceinline__ unsigned long long packdj(float d, int j) {
  unsigned db = __float_as_uint(d);
  db = (db & 0x80000000u) ? ~db : (db | 0x80000000u);
  return ((unsigned long long)db << 32) | (unsigned)j;
}

// np-exact d2: sequential fmaf chain (BLAS per-element order), validated r3.
__device__ __forceinline__ float exact_d2(const float* __restrict__ k,
                                          const float* __restrict__ q,
                                          float k2, float q2) {
  float c = 0.f;
#pragma unroll
  for (int t = 0; t < DDIM; ++t) c = fmaf(k[t], q[t], c);
  return __fsub_rn(__fadd_rn(k2, q2), __fmul_rn(2.0f, c));
}

__device__ __forceinline__ unsigned bf2pack(float a, float b) {
  __hip_bfloat16 ha = __float2bfloat16(a), hb = __float2bfloat16(b);
  unsigned short ua = *reinterpret_cast<unsigned short*>(&ha);
  unsigned short ub = *reinterpret_cast<unsigned short*>(&hb);
  return (unsigned)ua | ((unsigned)ub << 16);
}

// ---------------------------------------------------------------------------
// Kernel A: np-exact row norms + bf16 conversion (vectorized I/O).
// ---------------------------------------------------------------------------
__global__ __launch_bounds__(256) void knn_norms_np(
    const float* __restrict__ keys, const float* __restrict__ queries,
    int Nk, int Nq, float* __restrict__ k2, float* __restrict__ q2,
    float* __restrict__ sq, unsigned short* __restrict__ kbf,
    unsigned short* __restrict__ qbf) {
  int i = blockIdx.x * 256 + threadIdx.x;
  if (i >= Nk + Nq) return;
  bool isK = i < Nk;
  int r = isK ? i : i - Nk;
  const float4* row4 = reinterpret_cast<const float4*>(
      (isK ? keys : queries) + (size_t)r * DDIM);
  float p[DDIM]; unsigned hw[DDIM / 2];
#pragma unroll
  for (int t = 0; t < 16; ++t) {
    float4 v = row4[t];
    p[4 * t + 0] = __fmul_rn(v.x, v.x);
    p[4 * t + 1] = __fmul_rn(v.y, v.y);
    p[4 * t + 2] = __fmul_rn(v.z, v.z);
    p[4 * t + 3] = __fmul_rn(v.w, v.w);
    hw[2 * t + 0] = bf2pack(v.x, v.y);
    hw[2 * t + 1] = bf2pack(v.z, v.w);
  }
  float s = np_sum64(p);
  uint4* dst = reinterpret_cast<uint4*>((isK ? kbf : qbf) + (size_t)r * DDIM);
#pragma unroll
  for (int t = 0; t < 8; ++t)
    dst[t] = make_uint4(hw[4 * t], hw[4 * t + 1], hw[4 * t + 2], hw[4 * t + 3]);
  if (isK) k2[r] = s;
  else { q2[r] = s; sq[r] = sqrtf(s); }
}

// ---------------------------------------------------------------------------
// Kernel B (seed): np-exact top-16 over seed window, 16 slices x 128 queries.
// Validated structure (r4/r5). Writes slots 1..16.
// ---------------------------------------------------------------------------
__global__ __launch_bounds__(256) void knn_seed(
    const float* __restrict__ keys, const float* __restrict__ queries,
    const float* __restrict__ k2a, const float* __restrict__ q2a,
    float* __restrict__ pd, int* __restrict__ pi) {
  __shared__ float qs[2][CHUNK * DDIM];
  int tid = threadIdx.x;
  int kb = blockIdx.x & (NKB - 1);
  int sl = blockIdx.x >> 5;            // 0..15
  int key = kb * 256 + tid;

  float4 kreg[16];
  const float4* kp = reinterpret_cast<const float4*>(keys + (size_t)key * DDIM);
#pragma unroll
  for (int t = 0; t < 16; ++t) kreg[t] = kp[t];
  float myk2 = k2a[key];

  float bd[KSEL]; int bi[KSEL];
#pragma unroll
  for (int p = 0; p < KSEL; ++p) { bd[p] = FLT_MAX; bi[p] = INT_MAX; }

  int j0 = sl * SEED_LEN;
  const int NC = SEED_LEN / CHUNK;     // 4
  const float4* g0 = reinterpret_cast<const float4*>(queries + (size_t)j0 * DDIM);
  float4 s0 = g0[tid * 2], s1 = g0[tid * 2 + 1];

  for (int c = 0; c < NC; ++c) {
    float4* buf = reinterpret_cast<float4*>(qs[c & 1]);
    buf[tid * 2] = s0; buf[tid * 2 + 1] = s1;
    __syncthreads();
    if (c + 1 < NC) {
      const float4* gn = reinterpret_cast<const float4*>(
          queries + (size_t)(j0 + (c + 1) * CHUNK) * DDIM);
      s0 = gn[tid * 2]; s1 = gn[tid * 2 + 1];
    }
    const float* qb = qs[c & 1];
    int jb = j0 + c * CHUNK;
    for (int qq = 0; qq < CHUNK; qq += 4) {
      const float4* r0 = reinterpret_cast<const float4*>(qb + (qq + 0) * DDIM);
      const float4* r1 = reinterpret_cast<const float4*>(qb + (qq + 1) * DDIM);
      const float4* r2 = reinterpret_cast<const float4*>(qb + (qq + 2) * DDIM);
      const float4* r3 = reinterpret_cast<const float4*>(qb + (qq + 3) * DDIM);
      float c0 = 0.f, c1 = 0.f, c2 = 0.f, c3 = 0.f;
#pragma unroll
      for (int t = 0; t < 16; ++t) {
        float4 a0 = r0[t], a1 = r1[t], a2 = r2[t], a3 = r3[t];
        float k0 = kreg[t].x, k1 = kreg[t].y, k2v = kreg[t].z, k3 = kreg[t].w;
        c0 = fmaf(k0, a0.x, c0); c1 = fmaf(k0, a1.x, c1);
        c2 = fmaf(k0, a2.x, c2); c3 = fmaf(k0, a3.x, c3);
        c0 = fmaf(k1, a0.y, c0); c1 = fmaf(k1, a1.y, c1);
        c2 = fmaf(k1, a2.y, c2); c3 = fmaf(k1, a3.y, c3);
        c0 = fmaf(k2v, a0.z, c0); c1 = fmaf(k2v, a1.z, c1);
        c2 = fmaf(k2v, a2.z, c2); c3 = fmaf(k2v, a3.z, c3);
        c0 = fmaf(k3, a0.w, c0); c1 = fmaf(k3, a1.w, c1);
        c2 = fmaf(k3, a2.w, c2); c3 = fmaf(k3, a3.w, c3);
      }
      float dots[4] = {c0, c1, c2, c3};
#pragma unroll
      for (int u = 0; u < 4; ++u) {
        float d2 = __fsub_rn(__fadd_rn(myk2, q2a[jb + qq + u]),
                             __fmul_rn(2.0f, dots[u]));
        if (d2 < bd[KSEL - 1]) insert16(bd, bi, d2, jb + qq + u);
      }
    }
    __syncthreads();
  }
  size_t base = ((size_t)key * SLOTS + 1 + sl) * KSEL;
#pragma unroll
  for (int p = 0; p < KSEL; ++p) { pd[base + p] = bd[p]; pi[base + p] = bi[p]; }
}

// ---------------------------------------------------------------------------
// Kernel C (thresh): wave-per-key rank-selection merge of the 16 seed lists
// (256 entries) -> slot 0 sorted top-16 + per-key filter constants PS.
// Rank = count of strictly-smaller u64 packs; distinct j => strict order.
// ---------------------------------------------------------------------------
__global__ __launch_bounds__(256) void knn_thresh(
    const float* __restrict__ pd_in, const int* __restrict__ pi_in,
    const float* __restrict__ k2a,
    float* __restrict__ pd, int* __restrict__ pi, float2* __restrict__ PS) {
  __shared__ unsigned long long packs[4][256];
  int tid = threadIdx.x;
  int w = tid >> 6, lane = tid & 63;
  int key = blockIdx.x * 4 + w;
  size_t base = (size_t)key * SLOTS * KSEL;

  unsigned long long mine[4]; float md[4]; int mj[4];
#pragma unroll
  for (int r = 0; r < 4; ++r) {
    int e = KSEL + lane + 64 * r;          // 16..271 (slots 1..16)
    float d = pd_in[base + e]; int j = pi_in[base + e];
    md[r] = d; mj[r] = j;
    mine[r] = packdj(d, j);
    packs[w][lane + 64 * r] = mine[r];
  }
  __syncthreads();
  int cnt0 = 0, cnt1 = 0, cnt2 = 0, cnt3 = 0;
  for (int m = 0; m < 256; ++m) {
    unsigned long long pm = packs[w][m];
    cnt0 += pm < mine[0]; cnt1 += pm < mine[1];
    cnt2 += pm < mine[2]; cnt3 += pm < mine[3];
  }
  int cnt[4] = {cnt0, cnt1, cnt2, cnt3};
#pragma unroll
  for (int r = 0; r < 4; ++r) {
    if (cnt[r] < KSEL) {
      pd[base + cnt[r]] = md[r]; pi[base + cnt[r]] = mj[r];
      if (cnt[r] == KSEL - 1) {
        float k2 = k2a[key];
        PS[key] = make_float2(k2 - md[r] - C2, -C1 * sqrtf(k2));
      }
    }
  }
}

// ---------------------------------------------------------------------------
__global__ __launch_bounds__(256) void knn_zero(unsigned* __restrict__ p, int n) {
  int i = blockIdx.x * 256 + threadIdx.x;
  if (i < n) p[i] = 0u;
}

// ---------------------------------------------------------------------------
// Kernel D (MFMA filter): unchanged, validated r5.
// ---------------------------------------------------------------------------
__global__ __launch_bounds__(256) void knn_filter(
    const unsigned short* __restrict__ kbf, const unsigned short* __restrict__ qbf,
    const float* __restrict__ q2a, const float* __restrict__ sqa,
    const float2* __restrict__ PS,
    unsigned* __restrict__ cnt, unsigned short* __restrict__ cbuf, int CAP) {
  int tid = threadIdx.x;
  int lane = tid & 63, w = tid >> 6;
  int kb = blockIdx.x & (NKB - 1);
  int qt = blockIdx.x >> 5;
  int qbase = SEED_N + qt * 16;
  int kbase = kb * 256 + w * 64;
  int l16 = lane & 15, lg = lane >> 4;
  int q = qbase + l16;

  const short8* qrow = reinterpret_cast<const short8*>(qbf + (size_t)q * DDIM);
  short8 b0 = qrow[lg];
  short8 b1 = qrow[lg + 4];
  float q2l = q2a[q], sql = sqa[q];

  f32x4 acc[4];
#pragma unroll
  for (int s = 0; s < 4; ++s) {
    const short8* krow = reinterpret_cast<const short8*>(
        kbf + (size_t)(kbase + s * 16 + l16) * DDIM);
    short8 a0 = krow[lg], a1 = krow[lg + 4];
    f32x4 z = {0.f, 0.f, 0.f, 0.f};
    z = __builtin_amdgcn_mfma_f32_16x16x32_bf16(a0, b0, z, 0, 0, 0);
    z = __builtin_amdgcn_mfma_f32_16x16x32_bf16(a1, b1, z, 0, 0, 0);
    acc[s] = z;
  }
#pragma unroll
  for (int s = 0; s < 4; ++s) {
    int krow0 = kbase + s * 16 + lg * 4;
#pragma unroll
    for (int r = 0; r < 4; ++r) {
      float2 ps = PS[krow0 + r];
      float thr = 0.5f * ((ps.x + q2l) + ps.y * sql);
      if (acc[s][r] > thr) {
        int key = krow0 + r;
        unsigned pos = atomicAdd(&cnt[key], 1u);
        if (pos < (unsigned)CAP) cbuf[(size_t)key * CAP + pos] = (unsigned short)q;
      }
    }
  }
}

// ---------------------------------------------------------------------------
// Kernel E (recheck): wave-per-key. Lanes compute np-exact d2 for candidates
// in parallel -> LDS pack buffer (+16 seed entries) -> rank-count selection.
// Order-independent => deterministic despite atomic append order.
// Overflow => lane-parallel full scan + per-lane top-16 + same rank merge.
// ---------------------------------------------------------------------------
__global__ __launch_bounds__(256) void knn_recheck(
    const float* __restrict__ keys, const float* __restrict__ queries,
    const float* __restrict__ k2a, const float* __restrict__ q2a,
    const float* __restrict__ pd, const int* __restrict__ pi,
    const unsigned* __restrict__ cnt, const unsigned short* __restrict__ cbuf,
    int CAP, int Nq, float* __restrict__ outIdx) {
  __shared__ unsigned long long packs[4][RBUF];
  int tid = threadIdx.x;
  int w = tid >> 6, lane = tid & 63;
  int key = blockIdx.x * 4 + w;
  size_t base = (size_t)key * SLOTS * KSEL;
  float myk2 = k2a[key];
  const float* __restrict__ krow = keys + (size_t)key * DDIM;

  if (lane < KSEL)
    packs[w][lane] = packdj(pd[base + lane], pi[base + lane]);

  unsigned n = cnt[key];
  unsigned lim = (unsigned)((CAP < MERGE_MAX) ? CAP : MERGE_MAX);
  int N;
  if (n <= lim) {
    const unsigned short* mc = cbuf + (size_t)key * CAP;
    for (unsigned e = lane; e < n; e += 64) {
      int j = mc[e];
      float d2 = exact_d2(krow, queries + (size_t)j * DDIM, myk2, q2a[j]);
      packs[w][KSEL + e] = packdj(d2, j);
    }
    N = KSEL + (int)n;
  } else {
    // fallback: exact full scan, lane-parallel (correctness net)
    float bd[KSEL]; int bi[KSEL];
#pragma unroll
    for (int p = 0; p < KSEL; ++p) { bd[p] = FLT_MAX; bi[p] = INT_MAX; }
    for (int j = SEED_N + lane; j < Nq; j += 64) {
      float d2 = exact_d2(krow, queries + (size_t)j * DDIM, myk2, q2a[j]);
      if (d2 < bd[KSEL - 1] || (d2 == bd[KSEL - 1] && j < bi[KSEL - 1]))
        insert16(bd, bi, d2, j);
    }
#pragma unroll
    for (int p = 0; p < KSEL; ++p)
      packs[w][KSEL + lane * KSEL + p] = packdj(bd[p], bi[p]);
    N = KSEL + 64 * KSEL;
  }
  __syncthreads();
  for (int i = lane; i < N; i += 64) {
    unsigned long long mp = packs[w][i];
    int c = 0;
    for (int m = 0; m < N; ++m) c += packs[w][m] < mp;
    if (c < KSEL)
      outIdx[(size_t)key * KSEL + c] = (float)(int)(mp & 0xFFFFFFFFull);
  }
}

// ---------------------------------------------------------------------------
// Kernel F: recompute distances sum((k-q)^2) in f64, emit f32 (validated).
// ---------------------------------------------------------------------------
__global__ __launch_bounds__(256) void knn_dist_d(
    const float* __restrict__ keys, const float* __restrict__ queries,
    const float* __restrict__ outIdx, int Nk, float* __restrict__ outDist) {
  int e = blockIdx.x * 256 + threadIdx.x;
  if (e >= Nk * KSEL) return;
  int key = e >> 4;
  int id = (int)outIdx[e];
  const float* kp = keys + (size_t)key * DDIM;
  const float* qp = queries + (size_t)id * DDIM;
  double s = 0.0;
#pragma unroll
  for (int t = 0; t < DDIM; ++t) {
    double d = (double)kp[t] - (double)qp[t];
    s = fma(d, d, s);
  }
  outDist[e] = (float)s;
}

// ---------------------------------------------------------------------------
extern "C" void kernel_launch(void* const* d_in, const int* in_sizes, int n_in,
                              void* d_out, int out_size, void* d_ws, size_t ws_size,
                              hipStream_t stream) {
  const float* keys    = (const float*)d_in[0];
  const float* queries = (const float*)d_in[1];
  int Nk = in_sizes[0] / DDIM;   // 8192
  int Nq = in_sizes[1] / DDIM;   // 32768
  float* out = (float*)d_out;

  size_t listElems = (size_t)Nk * SLOTS * KSEL;
  char* wp = (char*)d_ws;
  float*          pd  = (float*)wp;                wp += listElems * 4;
  int*            pi  = (int*)wp;                  wp += listElems * 4;
  float*          k2  = (float*)wp;                wp += (size_t)Nk * 4;
  float*          q2  = (float*)wp;                wp += (size_t)Nq * 4;
  float*          sq  = (float*)wp;                wp += (size_t)Nq * 4;
  float2*         PS  = (float2*)wp;               wp += (size_t)Nk * 8;
  unsigned*       cnt = (unsigned*)wp;             wp += (size_t)Nk * 4;
  unsigned short* kbf = (unsigned short*)wp;       wp += (size_t)Nk * DDIM * 2;
  unsigned short* qbf = (unsigned short*)wp;       wp += (size_t)Nq * DDIM * 2;
  size_t fixedBytes = (size_t)(wp - (char*)d_ws);
  unsigned short* cbuf = (unsigned short*)wp;
  long long rem = (long long)ws_size - (long long)fixedBytes;
  int CAP = (int)(rem / (2 * (long long)Nk));
  if (CAP > 2048) CAP = 2048;
  if (CAP < 16) CAP = 16;

  int NQT = (Nq - SEED_N) / 16;   // 1920

  knn_norms_np<<<(Nk + Nq + 255) / 256, 256, 0, stream>>>(
      keys, queries, Nk, Nq, k2, q2, sq, kbf, qbf);
  knn_seed<<<NKB * SEED_SLICES, 256, 0, stream>>>(keys, queries, k2, q2, pd, pi);
  knn_thresh<<<Nk / 4, 256, 0, stream>>>(pd, pi, k2, pd, pi, PS);
  knn_zero<<<(Nk + 255) / 256, 256, 0, stream>>>(cnt, Nk);
  knn_filter<<<NKB * NQT, 256, 0, stream>>>(kbf, qbf, q2, sq, PS, cnt, cbuf, CAP);
  knn_recheck<<<Nk / 4, 256, 0, stream>>>(
      keys, queries, k2, q2, pd, pi, cnt, cbuf, CAP, Nq, out);
  knn_dist_d<<<(Nk * KSEL + 255) / 256, 256, 0, stream>>>(
      keys, queries, out, Nk, out + (size_t)Nk * KSEL);
}

// Round 7
// 736.128 us; speedup vs baseline: 13.7766x; 1.4380x over previous
//
#include <hip/hip_runtime.h>
#include <hip/hip_bf16.h>
#include <cfloat>
#include <climits>

#define DDIM 64
#define KSEL 16
#define NKB 32               // key blocks of 256 (seed)
#define SEED_SLICES 16
#define SEED_LEN 128         // seed window = 2048
#define SEED_N (SEED_SLICES * SEED_LEN)
#define SLOTS (1 + SEED_SLICES)
#define CHUNK 32
#define C1 0.017f            // > 2^-6: covers 2*bf16 dot error via Cauchy-Schwarz
#define C2 0.05f             // covers f32 accumulation + threshold rounding
#define MERGE_MAX 1008       // fast-path candidate limit for rank-merge buffer
#define RBUF (KSEL + 64 * KSEL)  // 1040 pack slots/wave (fallback worst case)

typedef __attribute__((ext_vector_type(8))) short short8;
typedef __attribute__((ext_vector_type(4))) float f32x4;

// ---------------------------------------------------------------------------
// numpy pairwise-sum emulation for n=64 contiguous f32 (validated r3-r6).
// ---------------------------------------------------------------------------
__device__ __forceinline__ float np_sum64(const float* p) {
  float lane[16];
#pragma unroll
  for (int j = 0; j < 16; ++j)
    lane[j] = __fadd_rn(__fadd_rn(p[j], p[16 + j]),
                        __fadd_rn(p[32 + j], p[48 + j]));
  float u[8];
#pragma unroll
  for (int j = 0; j < 8; ++j) u[j] = __fadd_rn(lane[j], lane[j + 8]);
  float w[4];
#pragma unroll
  for (int j = 0; j < 4; ++j) w[j] = __fadd_rn(u[j], u[j + 4]);
  return __fadd_rn(__fadd_rn(w[0], w[2]), __fadd_rn(w[1], w[3]));
}

__device__ __forceinline__ void insert16(float* bd, int* bi, float cd, int ci) {
#pragma unroll
  for (int p = 0; p < KSEL; ++p) {
    bool sm = (cd < bd[p]) || (cd == bd[p] && ci < bi[p]);
    float td = bd[p]; int ti = bi[p];
    bd[p] = sm ? cd : td; bi[p] = sm ? ci : ti;
    cd = sm ? td : cd;   ci = sm ? ti : ci;
  }
}

// Monotone map: lexicographic (d,j) ascending == u64 ascending (j distinct).
__device__ __forceinline__ unsigned long long packdj(float d, int j) {
  unsigned db = __float_as_uint(d);
  db = (db & 0x80000000u) ? ~db : (db | 0x80000000u);
  return ((unsigned long long)db << 32) | (unsigned)j;
}

// np-exact d2: sequential fmaf chain (BLAS per-element order), validated r3.
__device__ __forceinline__ float exact_d2(const float* __restrict__ k,
                                          const float* __restrict__ q,
                                          float k2, float q2) {
  float c = 0.f;
#pragma unroll
  for (int t = 0; t < DDIM; ++t) c = fmaf(k[t], q[t], c);
  return __fsub_rn(__fadd_rn(k2, q2), __fmul_rn(2.0f, c));
}

__device__ __forceinline__ unsigned bf2pack(float a, float b) {
  __hip_bfloat16 ha = __float2bfloat16(a), hb = __float2bfloat16(b);
  unsigned short ua = *reinterpret_cast<unsigned short*>(&ha);
  unsigned short ub = *reinterpret_cast<unsigned short*>(&hb);
  return (unsigned)ua | ((unsigned)ub << 16);
}

// ---------------------------------------------------------------------------
// Kernel A: np-exact row norms + bf16 conversion (vectorized I/O). Validated.
// ---------------------------------------------------------------------------
__global__ __launch_bounds__(256) void knn_norms_np(
    const float* __restrict__ keys, const float* __restrict__ queries,
    int Nk, int Nq, float* __restrict__ k2, float* __restrict__ q2,
    float* __restrict__ sq, unsigned short* __restrict__ kbf,
    unsigned short* __restrict__ qbf) {
  int i = blockIdx.x * 256 + threadIdx.x;
  if (i >= Nk + Nq) return;
  bool isK = i < Nk;
  int r = isK ? i : i - Nk;
  const float4* row4 = reinterpret_cast<const float4*>(
      (isK ? keys : queries) + (size_t)r * DDIM);
  float p[DDIM]; unsigned hw[DDIM / 2];
#pragma unroll
  for (int t = 0; t < 16; ++t) {
    float4 v = row4[t];
    p[4 * t + 0] = __fmul_rn(v.x, v.x);
    p[4 * t + 1] = __fmul_rn(v.y, v.y);
    p[4 * t + 2] = __fmul_rn(v.z, v.z);
    p[4 * t + 3] = __fmul_rn(v.w, v.w);
    hw[2 * t + 0] = bf2pack(v.x, v.y);
    hw[2 * t + 1] = bf2pack(v.z, v.w);
  }
  float s = np_sum64(p);
  uint4* dst = reinterpret_cast<uint4*>((isK ? kbf : qbf) + (size_t)r * DDIM);
#pragma unroll
  for (int t = 0; t < 8; ++t)
    dst[t] = make_uint4(hw[4 * t], hw[4 * t + 1], hw[4 * t + 2], hw[4 * t + 3]);
  if (isK) k2[r] = s;
  else { q2[r] = s; sq[r] = sqrtf(s); }
}

// ---------------------------------------------------------------------------
// Kernel B (seed): np-exact top-16 over seed window. Validated (r4-r6).
// ---------------------------------------------------------------------------
__global__ __launch_bounds__(256) void knn_seed(
    const float* __restrict__ keys, const float* __restrict__ queries,
    const float* __restrict__ k2a, const float* __restrict__ q2a,
    float* __restrict__ pd, int* __restrict__ pi) {
  __shared__ float qs[2][CHUNK * DDIM];
  int tid = threadIdx.x;
  int kb = blockIdx.x & (NKB - 1);
  int sl = blockIdx.x >> 5;            // 0..15
  int key = kb * 256 + tid;

  float4 kreg[16];
  const float4* kp = reinterpret_cast<const float4*>(keys + (size_t)key * DDIM);
#pragma unroll
  for (int t = 0; t < 16; ++t) kreg[t] = kp[t];
  float myk2 = k2a[key];

  float bd[KSEL]; int bi[KSEL];
#pragma unroll
  for (int p = 0; p < KSEL; ++p) { bd[p] = FLT_MAX; bi[p] = INT_MAX; }

  int j0 = sl * SEED_LEN;
  const int NC = SEED_LEN / CHUNK;     // 4
  const float4* g0 = reinterpret_cast<const float4*>(queries + (size_t)j0 * DDIM);
  float4 s0 = g0[tid * 2], s1 = g0[tid * 2 + 1];

  for (int c = 0; c < NC; ++c) {
    float4* buf = reinterpret_cast<float4*>(qs[c & 1]);
    buf[tid * 2] = s0; buf[tid * 2 + 1] = s1;
    __syncthreads();
    if (c + 1 < NC) {
      const float4* gn = reinterpret_cast<const float4*>(
          queries + (size_t)(j0 + (c + 1) * CHUNK) * DDIM);
      s0 = gn[tid * 2]; s1 = gn[tid * 2 + 1];
    }
    const float* qb = qs[c & 1];
    int jb = j0 + c * CHUNK;
    for (int qq = 0; qq < CHUNK; qq += 4) {
      const float4* r0 = reinterpret_cast<const float4*>(qb + (qq + 0) * DDIM);
      const float4* r1 = reinterpret_cast<const float4*>(qb + (qq + 1) * DDIM);
      const float4* r2 = reinterpret_cast<const float4*>(qb + (qq + 2) * DDIM);
      const float4* r3 = reinterpret_cast<const float4*>(qb + (qq + 3) * DDIM);
      float c0 = 0.f, c1 = 0.f, c2 = 0.f, c3 = 0.f;
#pragma unroll
      for (int t = 0; t < 16; ++t) {
        float4 a0 = r0[t], a1 = r1[t], a2 = r2[t], a3 = r3[t];
        float k0 = kreg[t].x, k1 = kreg[t].y, k2v = kreg[t].z, k3 = kreg[t].w;
        c0 = fmaf(k0, a0.x, c0); c1 = fmaf(k0, a1.x, c1);
        c2 = fmaf(k0, a2.x, c2); c3 = fmaf(k0, a3.x, c3);
        c0 = fmaf(k1, a0.y, c0); c1 = fmaf(k1, a1.y, c1);
        c2 = fmaf(k1, a2.y, c2); c3 = fmaf(k1, a3.y, c3);
        c0 = fmaf(k2v, a0.z, c0); c1 = fmaf(k2v, a1.z, c1);
        c2 = fmaf(k2v, a2.z, c2); c3 = fmaf(k2v, a3.z, c3);
        c0 = fmaf(k3, a0.w, c0); c1 = fmaf(k3, a1.w, c1);
        c2 = fmaf(k3, a2.w, c2); c3 = fmaf(k3, a3.w, c3);
      }
      float dots[4] = {c0, c1, c2, c3};
#pragma unroll
      for (int u = 0; u < 4; ++u) {
        float d2 = __fsub_rn(__fadd_rn(myk2, q2a[jb + qq + u]),
                             __fmul_rn(2.0f, dots[u]));
        if (d2 < bd[KSEL - 1]) insert16(bd, bi, d2, jb + qq + u);
      }
    }
    __syncthreads();
  }
  size_t base = ((size_t)key * SLOTS + 1 + sl) * KSEL;
#pragma unroll
  for (int p = 0; p < KSEL; ++p) { pd[base + p] = bd[p]; pi[base + p] = bi[p]; }
}

// ---------------------------------------------------------------------------
// Kernel C (thresh): wave-per-key rank-selection merge. Validated r6.
// ---------------------------------------------------------------------------
__global__ __launch_bounds__(256) void knn_thresh(
    const float* __restrict__ pd_in, const int* __restrict__ pi_in,
    const float* __restrict__ k2a,
    float* __restrict__ pd, int* __restrict__ pi, float2* __restrict__ PS) {
  __shared__ unsigned long long packs[4][256];
  int tid = threadIdx.x;
  int w = tid >> 6, lane = tid & 63;
  int key = blockIdx.x * 4 + w;
  size_t base = (size_t)key * SLOTS * KSEL;

  unsigned long long mine[4]; float md[4]; int mj[4];
#pragma unroll
  for (int r = 0; r < 4; ++r) {
    int e = KSEL + lane + 64 * r;
    float d = pd_in[base + e]; int j = pi_in[base + e];
    md[r] = d; mj[r] = j;
    mine[r] = packdj(d, j);
    packs[w][lane + 64 * r] = mine[r];
  }
  __syncthreads();
  int cnt0 = 0, cnt1 = 0, cnt2 = 0, cnt3 = 0;
  for (int m = 0; m < 256; ++m) {
    unsigned long long pm = packs[w][m];
    cnt0 += pm < mine[0]; cnt1 += pm < mine[1];
    cnt2 += pm < mine[2]; cnt3 += pm < mine[3];
  }
  int cnt[4] = {cnt0, cnt1, cnt2, cnt3};
#pragma unroll
  for (int r = 0; r < 4; ++r) {
    if (cnt[r] < KSEL) {
      pd[base + cnt[r]] = md[r]; pi[base + cnt[r]] = mj[r];
      if (cnt[r] == KSEL - 1) {
        float k2 = k2a[key];
        PS[key] = make_float2(k2 - md[r] - C2, -C1 * sqrtf(k2));
      }
    }
  }
}

// ---------------------------------------------------------------------------
__global__ __launch_bounds__(256) void knn_zero(unsigned* __restrict__ p, int n) {
  int i = blockIdx.x * 256 + threadIdx.x;
  if (i < n) p[i] = 0u;
}

// ---------------------------------------------------------------------------
// Kernel D (MFMA filter v2): wave = 64 keys x 64 queries (32 MFMA).
// Block = 4 waves, same 64 keys, 256 consecutive queries. A-frags + per-key
// filter constants loaded once per wave; branch-free hitmask epilogue with
// rare __ffs decode for atomic appends. Same validated MFMA layout as r5/r6.
// ---------------------------------------------------------------------------
__global__ __launch_bounds__(256) void knn_filter(
    const unsigned short* __restrict__ kbf, const unsigned short* __restrict__ qbf,
    const float* __restrict__ q2a, const float* __restrict__ sqa,
    const float2* __restrict__ PS,
    unsigned* __restrict__ cnt, unsigned short* __restrict__ cbuf, int CAP) {
  int tid = threadIdx.x;
  int lane = tid & 63, w = tid >> 6;
  int kb = blockIdx.x & 127;             // 128 key-strips of 64
  int qt = blockIdx.x >> 7;              // 0..119
  int kbase = kb * 64;
  int qbase = SEED_N + qt * 256 + w * 64;
  int l16 = lane & 15, lg = lane >> 4;

  // A-frags for 4 key sub-tiles (row = l16, k-halves lg*8 / 32+lg*8)
  short8 a0[4], a1[4];
#pragma unroll
  for (int s = 0; s < 4; ++s) {
    const short8* krow = reinterpret_cast<const short8*>(
        kbf + (size_t)(kbase + s * 16 + l16) * DDIM);
    a0[s] = krow[lg]; a1[s] = krow[lg + 4];
  }
  // Per-lane filter constants for my 16 keys (s x r)
  float psA[16], psB[16];
#pragma unroll
  for (int s = 0; s < 4; ++s)
#pragma unroll
    for (int r = 0; r < 4; ++r) {
      float2 ps = PS[kbase + s * 16 + lg * 4 + r];
      psA[s * 4 + r] = ps.x; psB[s * 4 + r] = ps.y;
    }

#pragma unroll
  for (int qs = 0; qs < 4; ++qs) {
    int q = qbase + qs * 16 + l16;
    const short8* qrow = reinterpret_cast<const short8*>(qbf + (size_t)q * DDIM);
    short8 b0 = qrow[lg], b1 = qrow[lg + 4];
    float q2l = q2a[q], sql = sqa[q];

    f32x4 acc[4];
#pragma unroll
    for (int s = 0; s < 4; ++s) {
      f32x4 z = {0.f, 0.f, 0.f, 0.f};
      z = __builtin_amdgcn_mfma_f32_16x16x32_bf16(a0[s], b0, z, 0, 0, 0);
      z = __builtin_amdgcn_mfma_f32_16x16x32_bf16(a1[s], b1, z, 0, 0, 0);
      acc[s] = z;
    }
    // branch-free hitmask: bit (s*4+r) set iff pair passes threshold
    unsigned m = 0;
#pragma unroll
    for (int s = 0; s < 4; ++s)
#pragma unroll
      for (int r = 0; r < 4; ++r) {
        float thr = 0.5f * ((psA[s * 4 + r] + q2l) + psB[s * 4 + r] * sql);
        m |= (acc[s][r] > thr) ? (1u << (s * 4 + r)) : 0u;
      }
    while (m) {
      int b = __ffs(m) - 1; m &= m - 1;
      int key = kbase + (b >> 2) * 16 + lg * 4 + (b & 3);
      unsigned pos = atomicAdd(&cnt[key], 1u);
      if (pos < (unsigned)CAP) cbuf[(size_t)key * CAP + pos] = (unsigned short)q;
    }
  }
}

// ---------------------------------------------------------------------------
// Kernel E (recheck): wave-per-key rank-selection. Validated r6.
// ---------------------------------------------------------------------------
__global__ __launch_bounds__(256) void knn_recheck(
    const float* __restrict__ keys, const float* __restrict__ queries,
    const float* __restrict__ k2a, const float* __restrict__ q2a,
    const float* __restrict__ pd, const int* __restrict__ pi,
    const unsigned* __restrict__ cnt, const unsigned short* __restrict__ cbuf,
    int CAP, int Nq, float* __restrict__ outIdx) {
  __shared__ unsigned long long packs[4][RBUF];
  int tid = threadIdx.x;
  int w = tid >> 6, lane = tid & 63;
  int key = blockIdx.x * 4 + w;
  size_t base = (size_t)key * SLOTS * KSEL;
  float myk2 = k2a[key];
  const float* __restrict__ krow = keys + (size_t)key * DDIM;

  if (lane < KSEL)
    packs[w][lane] = packdj(pd[base + lane], pi[base + lane]);

  unsigned n = cnt[key];
  unsigned lim = (unsigned)((CAP < MERGE_MAX) ? CAP : MERGE_MAX);
  int N;
  if (n <= lim) {
    const unsigned short* mc = cbuf + (size_t)key * CAP;
    for (unsigned e = lane; e < n; e += 64) {
      int j = mc[e];
      float d2 = exact_d2(krow, queries + (size_t)j * DDIM, myk2, q2a[j]);
      packs[w][KSEL + e] = packdj(d2, j);
    }
    N = KSEL + (int)n;
  } else {
    float bd[KSEL]; int bi[KSEL];
#pragma unroll
    for (int p = 0; p < KSEL; ++p) { bd[p] = FLT_MAX; bi[p] = INT_MAX; }
    for (int j = SEED_N + lane; j < Nq; j += 64) {
      float d2 = exact_d2(krow, queries + (size_t)j * DDIM, myk2, q2a[j]);
      if (d2 < bd[KSEL - 1] || (d2 == bd[KSEL - 1] && j < bi[KSEL - 1]))
        insert16(bd, bi, d2, j);
    }
#pragma unroll
    for (int p = 0; p < KSEL; ++p)
      packs[w][KSEL + lane * KSEL + p] = packdj(bd[p], bi[p]);
    N = KSEL + 64 * KSEL;
  }
  __syncthreads();
  for (int i = lane; i < N; i += 64) {
    unsigned long long mp = packs[w][i];
    int c = 0;
    for (int m = 0; m < N; ++m) c += packs[w][m] < mp;
    if (c < KSEL)
      outIdx[(size_t)key * KSEL + c] = (float)(int)(mp & 0xFFFFFFFFull);
  }
}

// ---------------------------------------------------------------------------
// Kernel F: recompute distances sum((k-q)^2) in f64, emit f32 (validated).
// ---------------------------------------------------------------------------
__global__ __launch_bounds__(256) void knn_dist_d(
    const float* __restrict__ keys, const float* __restrict__ queries,
    const float* __restrict__ outIdx, int Nk, float* __restrict__ outDist) {
  int e = blockIdx.x * 256 + threadIdx.x;
  if (e >= Nk * KSEL) return;
  int key = e >> 4;
  int id = (int)outIdx[e];
  const float* kp = keys + (size_t)key * DDIM;
  const float* qp = queries + (size_t)id * DDIM;
  double s = 0.0;
#pragma unroll
  for (int t = 0; t < DDIM; ++t) {
    double d = (double)kp[t] - (double)qp[t];
    s = fma(d, d, s);
  }
  outDist[e] = (float)s;
}

// ---------------------------------------------------------------------------
extern "C" void kernel_launch(void* const* d_in, const int* in_sizes, int n_in,
                              void* d_out, int out_size, void* d_ws, size_t ws_size,
                              hipStream_t stream) {
  const float* keys    = (const float*)d_in[0];
  const float* queries = (const float*)d_in[1];
  int Nk = in_sizes[0] / DDIM;   // 8192
  int Nq = in_sizes[1] / DDIM;   // 32768
  float* out = (float*)d_out;

  size_t listElems = (size_t)Nk * SLOTS * KSEL;
  char* wp = (char*)d_ws;
  float*          pd  = (float*)wp;                wp += listElems * 4;
  int*            pi  = (int*)wp;                  wp += listElems * 4;
  float*          k2  = (float*)wp;                wp += (size_t)Nk * 4;
  float*          q2  = (float*)wp;                wp += (size_t)Nq * 4;
  float*          sq  = (float*)wp;                wp += (size_t)Nq * 4;
  float2*         PS  = (float2*)wp;               wp += (size_t)Nk * 8;
  unsigned*       cnt = (unsigned*)wp;             wp += (size_t)Nk * 4;
  unsigned short* kbf = (unsigned short*)wp;       wp += (size_t)Nk * DDIM * 2;
  unsigned short* qbf = (unsigned short*)wp;       wp += (size_t)Nq * DDIM * 2;
  size_t fixedBytes = (size_t)(wp - (char*)d_ws);
  unsigned short* cbuf = (unsigned short*)wp;
  long long rem = (long long)ws_size - (long long)fixedBytes;
  int CAP = (int)(rem / (2 * (long long)Nk));
  if (CAP > 2048) CAP = 2048;
  if (CAP < 16) CAP = 16;

  int NQB = (Nq - SEED_N) / 256;   // 120 query-strips of 256

  knn_norms_np<<<(Nk + Nq + 255) / 256, 256, 0, stream>>>(
      keys, queries, Nk, Nq, k2, q2, sq, kbf, qbf);
  knn_seed<<<NKB * SEED_SLICES, 256, 0, stream>>>(keys, queries, k2, q2, pd, pi);
  knn_thresh<<<Nk / 4, 256, 0, stream>>>(pd, pi, k2, pd, pi, PS);
  knn_zero<<<(Nk + 255) / 256, 256, 0, stream>>>(cnt, Nk);
  knn_filter<<<128 * NQB, 256, 0, stream>>>(kbf, qbf, q2, sq, PS, cnt, cbuf, CAP);
  knn_recheck<<<Nk / 4, 256, 0, stream>>>(
      keys, queries, k2, q2, pd, pi, cnt, cbuf, CAP, Nq, out);
  knn_dist_d<<<(Nk * KSEL + 255) / 256, 256, 0, stream>>>(
      keys, queries, out, Nk, out + (size_t)Nk * KSEL);
}

// Round 8
// 576.371 us; speedup vs baseline: 17.5951x; 1.2772x over previous
//
#include <hip/hip_runtime.h>
#include <hip/hip_bf16.h>
#include <cfloat>
#include <climits>

#define DDIM 64
#define KSEL 16
#define WINDOW 2048          // T-estimation window
#define NCHUNK 16            // chunks of 128 in window
#define WSL 32               // window slices (seed2)
#define WSLEN 64             // queries per slice
#define SCAP 8               // per-thread append cap
#define C1 0.017f            // > 2^-6: covers 2*bf16 dot error via Cauchy-Schwarz
#define C2 0.05f             // covers f32 accumulation + threshold rounding
#define MERGE_MAX 1024
#define RBUF 1024

typedef __attribute__((ext_vector_type(8))) short short8;
typedef __attribute__((ext_vector_type(4))) float f32x4;

// ---------------------------------------------------------------------------
// numpy pairwise-sum emulation for n=64 contiguous f32 (validated r3-r7).
// ---------------------------------------------------------------------------
__device__ __forceinline__ float np_sum64(const float* p) {
  float lane[16];
#pragma unroll
  for (int j = 0; j < 16; ++j)
    lane[j] = __fadd_rn(__fadd_rn(p[j], p[16 + j]),
                        __fadd_rn(p[32 + j], p[48 + j]));
  float u[8];
#pragma unroll
  for (int j = 0; j < 8; ++j) u[j] = __fadd_rn(lane[j], lane[j + 8]);
  float w[4];
#pragma unroll
  for (int j = 0; j < 4; ++j) w[j] = __fadd_rn(u[j], u[j + 4]);
  return __fadd_rn(__fadd_rn(w[0], w[2]), __fadd_rn(w[1], w[3]));
}

__device__ __forceinline__ void insert16(float* bd, int* bi, float cd, int ci) {
#pragma unroll
  for (int p = 0; p < KSEL; ++p) {
    bool sm = (cd < bd[p]) || (cd == bd[p] && ci < bi[p]);
    float td = bd[p]; int ti = bi[p];
    bd[p] = sm ? cd : td; bi[p] = sm ? ci : ti;
    cd = sm ? td : cd;   ci = sm ? ti : ci;
  }
}

// Monotone map: lexicographic (d,j) ascending == u64 ascending (j distinct).
__device__ __forceinline__ unsigned long long packdj(float d, int j) {
  unsigned db = __float_as_uint(d);
  db = (db & 0x80000000u) ? ~db : (db | 0x80000000u);
  return ((unsigned long long)db << 32) | (unsigned)j;
}

__device__ __forceinline__ unsigned mapmono(float d) {
  unsigned db = __float_as_uint(d);
  return (db & 0x80000000u) ? ~db : (db | 0x80000000u);
}

__device__ __forceinline__ float unmapmono(unsigned m) {
  return (m & 0x80000000u) ? __uint_as_float(m & 0x7fffffffu)
                           : __uint_as_float(~m);
}

// np-exact d2: sequential fmaf chain (BLAS per-element order), validated r3.
__device__ __forceinline__ float exact_d2(const float* __restrict__ k,
                                          const float* __restrict__ q,
                                          float k2, float q2) {
  float c = 0.f;
#pragma unroll
  for (int t = 0; t < DDIM; ++t) c = fmaf(k[t], q[t], c);
  return __fsub_rn(__fadd_rn(k2, q2), __fmul_rn(2.0f, c));
}

__device__ __forceinline__ unsigned bf2pack(float a, float b) {
  __hip_bfloat16 ha = __float2bfloat16(a), hb = __float2bfloat16(b);
  unsigned short ua = *reinterpret_cast<unsigned short*>(&ha);
  unsigned short ub = *reinterpret_cast<unsigned short*>(&hb);
  return (unsigned)ua | ((unsigned)ub << 16);
}

// ---------------------------------------------------------------------------
// Kernel A: np-exact row norms + bf16 conversion + sqrt norms. Validated.
// ---------------------------------------------------------------------------
__global__ __launch_bounds__(256) void knn_norms_np(
    const float* __restrict__ keys, const float* __restrict__ queries,
    int Nk, int Nq, float* __restrict__ k2, float* __restrict__ q2,
    float* __restrict__ sk, float* __restrict__ sq,
    unsigned short* __restrict__ kbf, unsigned short* __restrict__ qbf) {
  int i = blockIdx.x * 256 + threadIdx.x;
  if (i >= Nk + Nq) return;
  bool isK = i < Nk;
  int r = isK ? i : i - Nk;
  const float4* row4 = reinterpret_cast<const float4*>(
      (isK ? keys : queries) + (size_t)r * DDIM);
  float p[DDIM]; unsigned hw[DDIM / 2];
#pragma unroll
  for (int t = 0; t < 16; ++t) {
    float4 v = row4[t];
    p[4 * t + 0] = __fmul_rn(v.x, v.x);
    p[4 * t + 1] = __fmul_rn(v.y, v.y);
    p[4 * t + 2] = __fmul_rn(v.z, v.z);
    p[4 * t + 3] = __fmul_rn(v.w, v.w);
    hw[2 * t + 0] = bf2pack(v.x, v.y);
    hw[2 * t + 1] = bf2pack(v.z, v.w);
  }
  float s = np_sum64(p);
  uint4* dst = reinterpret_cast<uint4*>((isK ? kbf : qbf) + (size_t)r * DDIM);
#pragma unroll
  for (int t = 0; t < 8; ++t)
    dst[t] = make_uint4(hw[4 * t], hw[4 * t + 1], hw[4 * t + 2], hw[4 * t + 3]);
  if (isK) { k2[r] = s; sk[r] = sqrtf(s); }
  else     { q2[r] = s; sq[r] = sqrtf(s); }
}

// ---------------------------------------------------------------------------
// Kernel B: init cmin = UINT_MAX, cnt = 0.
// ---------------------------------------------------------------------------
__global__ __launch_bounds__(256) void knn_init(
    unsigned* __restrict__ cmin, int nmin, unsigned* __restrict__ cnt, int ncnt) {
  int i = blockIdx.x * 256 + threadIdx.x;
  if (i < nmin) cmin[i] = 0xFFFFFFFFu;
  if (i < ncnt) cnt[i] = 0u;
}

// ---------------------------------------------------------------------------
// Kernel C (chunkmin): MFMA over keys x window. Per-(key, chunk-of-128) min
// of UPPER-bound distance u = (k2+q2-2*dot_bf16) + C1*sk*sq + C2 >= exact d2.
// Wave = 64 keys x 64 queries (one half-chunk). Cross-lane min + atomicMin.
// MFMA fragment layout identical to validated filter (r5-r7).
// ---------------------------------------------------------------------------
__global__ __launch_bounds__(256) void knn_chunkmin(
    const unsigned short* __restrict__ kbf, const unsigned short* __restrict__ qbf,
    const float* __restrict__ k2a, const float* __restrict__ ska,
    const float* __restrict__ q2a, const float* __restrict__ sqa,
    unsigned* __restrict__ cmin) {
  int tid = threadIdx.x, lane = tid & 63, w = tid >> 6;
  int kb = blockIdx.x & 127;             // 128 key-strips of 64
  int qt = blockIdx.x >> 7;              // 0..7 (window/256)
  int kbase = kb * 64;
  int qbase = qt * 256 + w * 64;
  int chunk = qbase >> 7;                // 0..15
  int l16 = lane & 15, lg = lane >> 4;

  short8 a0[4], a1[4];
#pragma unroll
  for (int s = 0; s < 4; ++s) {
    const short8* krow = reinterpret_cast<const short8*>(
        kbf + (size_t)(kbase + s * 16 + l16) * DDIM);
    a0[s] = krow[lg]; a1[s] = krow[lg + 4];
  }
  float KA[16], KB[16];
#pragma unroll
  for (int s = 0; s < 4; ++s)
#pragma unroll
    for (int r = 0; r < 4; ++r) {
      int kk = kbase + s * 16 + lg * 4 + r;
      KA[s * 4 + r] = k2a[kk] + C2;
      KB[s * 4 + r] = C1 * ska[kk];
    }
  float mreg[16];
#pragma unroll
  for (int i = 0; i < 16; ++i) mreg[i] = FLT_MAX;

#pragma unroll
  for (int qs = 0; qs < 4; ++qs) {
    int q = qbase + qs * 16 + l16;
    const short8* qrow = reinterpret_cast<const short8*>(qbf + (size_t)q * DDIM);
    short8 b0 = qrow[lg], b1 = qrow[lg + 4];
    float q2l = q2a[q], sql = sqa[q];
    f32x4 acc[4];
#pragma unroll
    for (int s = 0; s < 4; ++s) {
      f32x4 z = {0.f, 0.f, 0.f, 0.f};
      z = __builtin_amdgcn_mfma_f32_16x16x32_bf16(a0[s], b0, z, 0, 0, 0);
      z = __builtin_amdgcn_mfma_f32_16x16x32_bf16(a1[s], b1, z, 0, 0, 0);
      acc[s] = z;
    }
#pragma unroll
    for (int s = 0; s < 4; ++s)
#pragma unroll
      for (int r = 0; r < 4; ++r) {
        int i = s * 4 + r;
        float u = fmaf(KB[i], sql, KA[i] + q2l) - 2.0f * acc[s][r];
        mreg[i] = fminf(mreg[i], u);
      }
  }
  // min across the 16 lanes sharing lg (query columns)
#pragma unroll
  for (int m = 1; m < 16; m <<= 1)
#pragma unroll
    for (int i = 0; i < 16; ++i)
      mreg[i] = fminf(mreg[i], __shfl_xor(mreg[i], m));
  if (l16 == 0) {
#pragma unroll
    for (int i = 0; i < 16; ++i) {
      int kk = kbase + (i >> 2) * 16 + lg * 4 + (i & 3);
      atomicMin(&cmin[(size_t)kk * NCHUNK + chunk], mapmono(mreg[i]));
    }
  }
}

// ---------------------------------------------------------------------------
// Kernel D (trough): T_rough[key] = max over 16 chunk minima (valid upper
// bound on window's exact 16th-smallest d2: 16 values <= it).
// ---------------------------------------------------------------------------
__global__ __launch_bounds__(256) void knn_trough(
    const unsigned* __restrict__ cmin, float* __restrict__ PR, int Nk) {
  int k = blockIdx.x * 256 + threadIdx.x;
  if (k >= Nk) return;
  unsigned m = 0;
#pragma unroll
  for (int c = 0; c < NCHUNK; ++c) {
    unsigned v = cmin[(size_t)k * NCHUNK + c];
    m = v > m ? v : m;
  }
  PR[k] = unmapmono(m);
}

// ---------------------------------------------------------------------------
// Kernel E (seed2): np-exact d2 over window, branchless-cheap append of
// entries with d2 <= T_rough (E~1.7/thread, cap 8; truncation => looser but
// still valid T downstream). Round-3-validated dot structure (global
// broadcast query loads, 4-query FMA interleave).
// ---------------------------------------------------------------------------
__global__ __launch_bounds__(256) void knn_seed2(
    const float* __restrict__ keys, const float* __restrict__ queries,
    const float* __restrict__ k2a, const float* __restrict__ q2a,
    const float* __restrict__ PR, unsigned long long* __restrict__ spack) {
  __shared__ unsigned long long lbuf[256 * SCAP];   // 16 KB
  int tid = threadIdx.x;
  int kb = blockIdx.x & 31, sl = blockIdx.x >> 5;   // 32 kb x 32 slices
  int key = kb * 256 + tid;

  float4 kreg[16];
  const float4* kp = reinterpret_cast<const float4*>(keys + (size_t)key * DDIM);
#pragma unroll
  for (int t = 0; t < 16; ++t) kreg[t] = kp[t];
  float myk2 = k2a[key], pr = PR[key];
  int cnt = 0;

  int j0 = sl * WSLEN;
  for (int j = j0; j < j0 + WSLEN; j += 4) {
    const float4* q40 = reinterpret_cast<const float4*>(queries + (size_t)(j + 0) * DDIM);
    const float4* q41 = reinterpret_cast<const float4*>(queries + (size_t)(j + 1) * DDIM);
    const float4* q42 = reinterpret_cast<const float4*>(queries + (size_t)(j + 2) * DDIM);
    const float4* q43 = reinterpret_cast<const float4*>(queries + (size_t)(j + 3) * DDIM);
    float c0 = 0.f, c1 = 0.f, c2 = 0.f, c3 = 0.f;
#pragma unroll
    for (int t = 0; t < 16; ++t) {
      float4 a0 = q40[t], a1 = q41[t], a2 = q42[t], a3 = q43[t];
      float k0 = kreg[t].x, k1 = kreg[t].y, k2v = kreg[t].z, k3 = kreg[t].w;
      c0 = fmaf(k0, a0.x, c0); c1 = fmaf(k0, a1.x, c1);
      c2 = fmaf(k0, a2.x, c2); c3 = fmaf(k0, a3.x, c3);
      c0 = fmaf(k1, a0.y, c0); c1 = fmaf(k1, a1.y, c1);
      c2 = fmaf(k1, a2.y, c2); c3 = fmaf(k1, a3.y, c3);
      c0 = fmaf(k2v, a0.z, c0); c1 = fmaf(k2v, a1.z, c1);
      c2 = fmaf(k2v, a2.z, c2); c3 = fmaf(k2v, a3.z, c3);
      c0 = fmaf(k3, a0.w, c0); c1 = fmaf(k3, a1.w, c1);
      c2 = fmaf(k3, a2.w, c2); c3 = fmaf(k3, a3.w, c3);
    }
    float dots[4] = {c0, c1, c2, c3};
#pragma unroll
    for (int u = 0; u < 4; ++u) {
      float d2 = __fsub_rn(__fadd_rn(myk2, q2a[j + u]),
                           __fmul_rn(2.0f, dots[u]));
      if (d2 <= pr) {
        lbuf[tid * SCAP + (cnt < SCAP ? cnt : SCAP - 1)] = packdj(d2, j + u);
        cnt++;
      }
    }
  }
  int wn = cnt < SCAP ? cnt : SCAP;
  unsigned long long* dst =
      spack + ((size_t)(kb * WSL + sl) * 256 + tid) * SCAP;
#pragma unroll
  for (int e = 0; e < SCAP; ++e)
    dst[e] = (e < wn) ? lbuf[tid * SCAP + e] : ~0ull;
}

// ---------------------------------------------------------------------------
// Kernel F (thresh2): wave-per-key rank-count over the 256 appended packs ->
// T = 16th-smallest entry (subset-of-window 16th => valid upper bound on the
// global exact 16th). Fallback to T_rough if <16 entries. Writes PS.
// ---------------------------------------------------------------------------
__global__ __launch_bounds__(256) void knn_thresh2(
    const unsigned long long* __restrict__ spack, const float* __restrict__ PR,
    const float* __restrict__ k2a, const float* __restrict__ ska,
    float2* __restrict__ PS) {
  __shared__ unsigned long long packs[4][WSL * SCAP];
  __shared__ float Tsh[4];
  int tid = threadIdx.x, w = tid >> 6, lane = tid & 63;
  int key = blockIdx.x * 4 + w;
  int kb = key >> 8, t = key & 255;

  unsigned long long mine[4];
#pragma unroll
  for (int r = 0; r < 4; ++r) {
    int e = lane + 64 * r;
    int sl = e >> 3, p = e & 7;
    mine[r] = spack[((size_t)(kb * WSL + sl) * 256 + t) * SCAP + p];
    packs[w][e] = mine[r];
  }
  if (lane == 0) Tsh[w] = PR[key];
  __syncthreads();
  int c0 = 0, c1 = 0, c2 = 0, c3 = 0;
  for (int m = 0; m < WSL * SCAP; ++m) {
    unsigned long long pm = packs[w][m];
    c0 += pm < mine[0]; c1 += pm < mine[1];
    c2 += pm < mine[2]; c3 += pm < mine[3];
  }
  int c[4] = {c0, c1, c2, c3};
  __syncthreads();
#pragma unroll
  for (int r = 0; r < 4; ++r)
    if (c[r] == KSEL - 1 && mine[r] != ~0ull)
      Tsh[w] = unmapmono((unsigned)(mine[r] >> 32));
  __syncthreads();
  if (lane == 0) {
    float T = Tsh[w];
    PS[key] = make_float2(k2a[key] - T - C2, -C1 * ska[key]);
  }
}

// ---------------------------------------------------------------------------
// Kernel G (MFMA filter): now over ALL queries [0, Nq). Validated r7
// structure: wave = 64 keys x 64 queries, hitmask epilogue, atomic append.
// ---------------------------------------------------------------------------
__global__ __launch_bounds__(256) void knn_filter(
    const unsigned short* __restrict__ kbf, const unsigned short* __restrict__ qbf,
    const float* __restrict__ q2a, const float* __restrict__ sqa,
    const float2* __restrict__ PS,
    unsigned* __restrict__ cnt, unsigned short* __restrict__ cbuf, int CAP) {
  int tid = threadIdx.x;
  int lane = tid & 63, w = tid >> 6;
  int kb = blockIdx.x & 127;             // 128 key-strips of 64
  int qt = blockIdx.x >> 7;              // 0..127
  int kbase = kb * 64;
  int qbase = qt * 256 + w * 64;
  int l16 = lane & 15, lg = lane >> 4;

  short8 a0[4], a1[4];
#pragma unroll
  for (int s = 0; s < 4; ++s) {
    const short8* krow = reinterpret_cast<const short8*>(
        kbf + (size_t)(kbase + s * 16 + l16) * DDIM);
    a0[s] = krow[lg]; a1[s] = krow[lg + 4];
  }
  float psA[16], psB[16];
#pragma unroll
  for (int s = 0; s < 4; ++s)
#pragma unroll
    for (int r = 0; r < 4; ++r) {
      float2 ps = PS[kbase + s * 16 + lg * 4 + r];
      psA[s * 4 + r] = ps.x; psB[s * 4 + r] = ps.y;
    }

#pragma unroll
  for (int qs = 0; qs < 4; ++qs) {
    int q = qbase + qs * 16 + l16;
    const short8* qrow = reinterpret_cast<const short8*>(qbf + (size_t)q * DDIM);
    short8 b0 = qrow[lg], b1 = qrow[lg + 4];
    float q2l = q2a[q], sql = sqa[q];

    f32x4 acc[4];
#pragma unroll
    for (int s = 0; s < 4; ++s) {
      f32x4 z = {0.f, 0.f, 0.f, 0.f};
      z = __builtin_amdgcn_mfma_f32_16x16x32_bf16(a0[s], b0, z, 0, 0, 0);
      z = __builtin_amdgcn_mfma_f32_16x16x32_bf16(a1[s], b1, z, 0, 0, 0);
      acc[s] = z;
    }
    unsigned m = 0;
#pragma unroll
    for (int s = 0; s < 4; ++s)
#pragma unroll
      for (int r = 0; r < 4; ++r) {
        float thr = 0.5f * ((psA[s * 4 + r] + q2l) + psB[s * 4 + r] * sql);
        m |= (acc[s][r] > thr) ? (1u << (s * 4 + r)) : 0u;
      }
    while (m) {
      int b = __ffs(m) - 1; m &= m - 1;
      int key = kbase + (b >> 2) * 16 + lg * 4 + (b & 3);
      unsigned pos = atomicAdd(&cnt[key], 1u);
      if (pos < (unsigned)CAP) cbuf[(size_t)key * CAP + pos] = (unsigned short)q;
    }
  }
}

// ---------------------------------------------------------------------------
// Kernel H (recheck): wave-per-key. np-exact d2 per candidate, rank-count
// selection -> final indices. Order-independent (deterministic). Overflow =>
// lane-parallel full-scan fallback (correctness net).
// ---------------------------------------------------------------------------
__global__ __launch_bounds__(256) void knn_recheck(
    const float* __restrict__ keys, const float* __restrict__ queries,
    const float* __restrict__ k2a, const float* __restrict__ q2a,
    const unsigned* __restrict__ cnt, const unsigned short* __restrict__ cbuf,
    int CAP, int Nq, float* __restrict__ outIdx) {
  __shared__ unsigned long long packs[4][RBUF];
  int tid = threadIdx.x;
  int w = tid >> 6, lane = tid & 63;
  int key = blockIdx.x * 4 + w;
  float myk2 = k2a[key];
  const float* __restrict__ krow = keys + (size_t)key * DDIM;

  unsigned n = cnt[key];
  unsigned lim = (unsigned)((CAP < MERGE_MAX) ? CAP : MERGE_MAX);
  int N;
  if (n <= lim) {
    const unsigned short* mc = cbuf + (size_t)key * CAP;
    for (unsigned e = lane; e < n; e += 64) {
      int j = mc[e];
      float d2 = exact_d2(krow, queries + (size_t)j * DDIM, myk2, q2a[j]);
      packs[w][e] = packdj(d2, j);
    }
    N = (int)n;
  } else {
    float bd[KSEL]; int bi[KSEL];
#pragma unroll
    for (int p = 0; p < KSEL; ++p) { bd[p] = FLT_MAX; bi[p] = INT_MAX; }
    for (int j = lane; j < Nq; j += 64) {
      float d2 = exact_d2(krow, queries + (size_t)j * DDIM, myk2, q2a[j]);
      if (d2 < bd[KSEL - 1] || (d2 == bd[KSEL - 1] && j < bi[KSEL - 1]))
        insert16(bd, bi, d2, j);
    }
#pragma unroll
    for (int p = 0; p < KSEL; ++p)
      packs[w][lane * KSEL + p] = packdj(bd[p], bi[p]);
    N = 64 * KSEL;
  }
  __syncthreads();
  for (int i = lane; i < N; i += 64) {
    unsigned long long mp = packs[w][i];
    int c = 0;
    for (int m = 0; m < N; ++m) c += packs[w][m] < mp;
    if (c < KSEL)
      outIdx[(size_t)key * KSEL + c] = (float)(int)(mp & 0xFFFFFFFFull);
  }
}

// ---------------------------------------------------------------------------
// Kernel I: recompute distances sum((k-q)^2) in f64, emit f32 (validated).
// ---------------------------------------------------------------------------
__global__ __launch_bounds__(256) void knn_dist_d(
    const float* __restrict__ keys, const float* __restrict__ queries,
    const float* __restrict__ outIdx, int Nk, float* __restrict__ outDist) {
  int e = blockIdx.x * 256 + threadIdx.x;
  if (e >= Nk * KSEL) return;
  int key = e >> 4;
  int id = (int)outIdx[e];
  const float* kp = keys + (size_t)key * DDIM;
  const float* qp = queries + (size_t)id * DDIM;
  double s = 0.0;
#pragma unroll
  for (int t = 0; t < DDIM; ++t) {
    double d = (double)kp[t] - (double)qp[t];
    s = fma(d, d, s);
  }
  outDist[e] = (float)s;
}

// ---------------------------------------------------------------------------
extern "C" void kernel_launch(void* const* d_in, const int* in_sizes, int n_in,
                              void* d_out, int out_size, void* d_ws, size_t ws_size,
                              hipStream_t stream) {
  const float* keys    = (const float*)d_in[0];
  const float* queries = (const float*)d_in[1];
  int Nk = in_sizes[0] / DDIM;   // 8192
  int Nq = in_sizes[1] / DDIM;   // 32768
  float* out = (float*)d_out;

  // Workspace layout
  char* wp = (char*)d_ws;
  unsigned long long* spack = (unsigned long long*)wp;
  wp += (size_t)Nk * WSL * SCAP * 8;                       // 16.78 MB
  float*    k2  = (float*)wp;  wp += (size_t)Nk * 4;
  float*    q2  = (float*)wp;  wp += (size_t)Nq * 4;
  float*    sk  = (float*)wp;  wp += (size_t)Nk * 4;
  float*    sq  = (float*)wp;  wp += (size_t)Nq * 4;
  float*    PR  = (float*)wp;  wp += (size_t)Nk * 4;
  float2*   PS  = (float2*)wp; wp += (size_t)Nk * 8;
  unsigned* cnt = (unsigned*)wp; wp += (size_t)Nk * 4;
  unsigned* cmin = (unsigned*)wp; wp += (size_t)Nk * NCHUNK * 4;
  unsigned short* kbf = (unsigned short*)wp; wp += (size_t)Nk * DDIM * 2;
  unsigned short* qbf = (unsigned short*)wp; wp += (size_t)Nq * DDIM * 2;
  size_t fixedBytes = (size_t)(wp - (char*)d_ws);
  unsigned short* cbuf = (unsigned short*)wp;
  long long rem = (long long)ws_size - (long long)fixedBytes;
  int CAP = (int)(rem / (2 * (long long)Nk));
  if (CAP > 2048) CAP = 2048;
  if (CAP < 16) CAP = 16;

  int nInit = Nk * NCHUNK;                 // 131072 (>= Nk)
  knn_init<<<(nInit + 255) / 256, 256, 0, stream>>>(cmin, nInit, cnt, Nk);
  knn_norms_np<<<(Nk + Nq + 255) / 256, 256, 0, stream>>>(
      keys, queries, Nk, Nq, k2, q2, sk, sq, kbf, qbf);
  knn_chunkmin<<<128 * (WINDOW / 256), 256, 0, stream>>>(
      kbf, qbf, k2, sk, q2, sq, cmin);
  knn_trough<<<(Nk + 255) / 256, 256, 0, stream>>>(cmin, PR, Nk);
  knn_seed2<<<32 * WSL, 256, 0, stream>>>(keys, queries, k2, q2, PR, spack);
  knn_thresh2<<<Nk / 4, 256, 0, stream>>>(spack, PR, k2, sk, PS);
  knn_filter<<<128 * (Nq / 256), 256, 0, stream>>>(
      kbf, qbf, q2, sq, PS, cnt, cbuf, CAP);
  knn_recheck<<<Nk / 4, 256, 0, stream>>>(
      keys, queries, k2, q2, cnt, cbuf, CAP, Nq, out);
  knn_dist_d<<<(Nk * KSEL + 255) / 256, 256, 0, stream>>>(
      keys, queries, out, Nk, out + (size_t)Nk * KSEL);
}